// Round 1
// baseline (1337.975 us; speedup 1.0000x reference)
//
#include <hip/hip_runtime.h>
#include <cstdint>

#define NN 100000
#define NE 1600000
#define DI 9
#define DD 128
#define NH 8
#define NG 1000

__device__ __forceinline__ float leaky(float x){ return x > 0.f ? x : 0.2f*x; }

// ---------------- CSR build ----------------
__global__ void k_count(const int* __restrict__ dst, int* __restrict__ cnt){
  int i = blockIdx.x*blockDim.x + threadIdx.x;
  if (i < NE) atomicAdd(&cnt[dst[i]], 1);
}

__global__ __launch_bounds__(512) void k_scan1(const int* __restrict__ cnt, int* __restrict__ rowptr,
                                               int* __restrict__ partial){
  __shared__ int sh[512];
  int tid = threadIdx.x;
  int i = blockIdx.x*512 + tid;
  int v = (i < NN) ? cnt[i] : 0;
  sh[tid] = v;
  __syncthreads();
  for (int off = 1; off < 512; off <<= 1){
    int t = (tid >= off) ? sh[tid-off] : 0;
    __syncthreads();
    sh[tid] += t;
    __syncthreads();
  }
  if (i < NN) rowptr[i] = sh[tid] - v;          // exclusive
  if (tid == 511) partial[blockIdx.x] = sh[511]; // block total
}

__global__ __launch_bounds__(256) void k_scan2(int* partial, int nb){
  __shared__ int sh[256];
  int tid = threadIdx.x;
  int v = (tid < nb) ? partial[tid] : 0;
  sh[tid] = v;
  __syncthreads();
  for (int off = 1; off < 256; off <<= 1){
    int t = (tid >= off) ? sh[tid-off] : 0;
    __syncthreads();
    sh[tid] += t;
    __syncthreads();
  }
  if (tid < nb) partial[tid] = sh[tid] - v;      // exclusive
}

__global__ __launch_bounds__(512) void k_scan3(int* __restrict__ rowptr, int* __restrict__ wo,
                                               const int* __restrict__ partial, const int* __restrict__ cnt){
  int i = blockIdx.x*512 + threadIdx.x;
  if (i < NN){
    int v = rowptr[i] + partial[blockIdx.x];
    rowptr[i] = v;
    wo[i] = v;
    if (i == NN-1) rowptr[NN] = v + cnt[i];
  }
}

__global__ void k_fill(const int* __restrict__ src, const int* __restrict__ dst,
                       int* __restrict__ wo, int* __restrict__ col){
  int i = blockIdx.x*blockDim.x + threadIdx.x;
  if (i < NE){
    int p = atomicAdd(&wo[dst[i]], 1);
    col[p] = src[i];
  }
}

// ---------------- GAT1 linear (x@W1) + attention logits ----------------
__global__ __launch_bounds__(128) void k_lin1(const float* __restrict__ x, const float* __restrict__ W1,
    const float* __restrict__ as1, const float* __restrict__ ad1,
    float* __restrict__ t1, float* __restrict__ al_s, float* __restrict__ al_d){
  int n = blockIdx.x;
  int c = threadIdx.x;
  const float* xr = x + n*DI;
  float t = 0.f;
  #pragma unroll
  for (int k = 0; k < DI; ++k) t = fmaf(xr[k], W1[k*DD+c], t);
  t1[(size_t)n*DD + c] = t;
  float vs = t * as1[c];   // a_src1 flat index == channel
  float vd = t * ad1[c];
  #pragma unroll
  for (int m = 8; m >= 1; m >>= 1){ vs += __shfl_xor(vs, m, 16); vd += __shfl_xor(vd, m, 16); }
  if ((c & 15) == 0){
    al_s[n*NH + (c>>4)] = vs;
    al_d[n*NH + (c>>4)] = vd;
  }
}

// ---------------- GAT1 aggregation (8 heads), + b1, ReLU ----------------
__global__ __launch_bounds__(128) void k_gat1(const float* __restrict__ t1,
    const float* __restrict__ al_s, const float* __restrict__ al_d,
    const int* __restrict__ rowptr, const int* __restrict__ col,
    const float* __restrict__ b1, float* __restrict__ out){
  int n = blockIdx.x;
  int c = threadIdx.x;
  int h = c >> 4;
  float ald = al_d[n*NH + h];
  float es = leaky(al_s[n*NH + h] + ald);   // self loop
  int beg = rowptr[n], end = rowptr[n+1];
  float m = es;
  for (int e = beg; e < end; ++e){
    int s = col[e];
    m = fmaxf(m, leaky(al_s[s*NH + h] + ald));
  }
  float a0  = __expf(es - m);
  float den = a0;
  float acc = a0 * t1[(size_t)n*DD + c];
  for (int e = beg; e < end; ++e){
    int s = col[e];
    float a = __expf(leaky(al_s[s*NH + h] + ald) - m);
    den += a;
    acc = fmaf(a, t1[(size_t)s*DD + c], acc);
  }
  float v = acc/(den + 1e-16f) + b1[c];
  out[(size_t)n*DD + c] = fmaxf(v, 0.f);
}

// ---------------- GAT2 attention logits (1 head over 128 ch) ----------------
__global__ __launch_bounds__(256) void k_al2(const float* __restrict__ t2,
    const float* __restrict__ as2, const float* __restrict__ ad2,
    float* __restrict__ al_s, float* __restrict__ al_d){
  int n = blockIdx.x*4 + (threadIdx.x >> 6);
  if (n >= NN) return;
  int lane = threadIdx.x & 63;
  const float* r = t2 + (size_t)n*DD;
  float vs = r[lane]*as2[lane] + r[lane+64]*as2[lane+64];
  float vd = r[lane]*ad2[lane] + r[lane+64]*ad2[lane+64];
  #pragma unroll
  for (int m = 32; m >= 1; m >>= 1){ vs += __shfl_xor(vs, m, 64); vd += __shfl_xor(vd, m, 64); }
  if (lane == 0){ al_s[n] = vs; al_d[n] = vd; }
}

// ---------------- GAT2 aggregation (1 head), + b2 (no relu) ----------------
__global__ __launch_bounds__(128) void k_gat2(const float* __restrict__ t2,
    const float* __restrict__ al_s, const float* __restrict__ al_d,
    const int* __restrict__ rowptr, const int* __restrict__ col,
    const float* __restrict__ b2, float* __restrict__ out){
  int n = blockIdx.x;
  int c = threadIdx.x;
  float ald = al_d[n];
  float es = leaky(al_s[n] + ald);
  int beg = rowptr[n], end = rowptr[n+1];
  float m = es;
  for (int e = beg; e < end; ++e) m = fmaxf(m, leaky(al_s[col[e]] + ald));
  float a0  = __expf(es - m);
  float den = a0;
  float acc = a0 * t2[(size_t)n*DD + c];
  for (int e = beg; e < end; ++e){
    int s = col[e];
    float a = __expf(leaky(al_s[s] + ald) - m);
    den += a;
    acc = fmaf(a, t2[(size_t)s*DD + c], acc);
  }
  out[(size_t)n*DD + c] = acc/(den + 1e-16f) + b2[c];
}

// ---------------- 128x128 GEMM, register-tiled, optional bias/res/relu ----------------
template<bool RELU, bool BIAS, bool RES>
__global__ __launch_bounds__(256) void k_gemm128(const float* __restrict__ X, const float* __restrict__ W,
    const float* __restrict__ bias, const float* __restrict__ res, float* __restrict__ out, int nrows){
  __shared__ __align__(16) float Xs[DD][132];   // [k][r], padded rows
  int tid = threadIdx.x;
  int n0 = blockIdx.x * 128;
  {
    int r  = tid >> 1;
    int c0 = (tid & 1) * 64;
    int n  = n0 + r;
    if (n < nrows){
      const float* xp = X + (size_t)n*DD + c0;
      #pragma unroll
      for (int i = 0; i < 16; ++i){
        float4 v = *(const float4*)(xp + i*4);
        int c = c0 + i*4;
        Xs[c][r] = v.x; Xs[c+1][r] = v.y; Xs[c+2][r] = v.z; Xs[c+3][r] = v.w;
      }
    } else {
      #pragma unroll
      for (int i = 0; i < 16; ++i){
        int c = c0 + i*4;
        Xs[c][r] = 0.f; Xs[c+1][r] = 0.f; Xs[c+2][r] = 0.f; Xs[c+3][r] = 0.f;
      }
    }
  }
  __syncthreads();
  int tc = tid & 31, tr = tid >> 5;
  int j0 = tc*4, r0 = tr*16;
  float4 acc[16];
  #pragma unroll
  for (int i = 0; i < 16; ++i) acc[i] = make_float4(0.f,0.f,0.f,0.f);
  #pragma unroll 2
  for (int k = 0; k < DD; ++k){
    float4 w4 = *(const float4*)(W + k*DD + j0);
    #pragma unroll
    for (int ii = 0; ii < 4; ++ii){
      float4 x4 = *(const float4*)&Xs[k][r0 + ii*4];
      float xs[4] = {x4.x, x4.y, x4.z, x4.w};
      #pragma unroll
      for (int jj = 0; jj < 4; ++jj){
        float xv = xs[jj];
        float4& a = acc[ii*4+jj];
        a.x = fmaf(xv, w4.x, a.x);
        a.y = fmaf(xv, w4.y, a.y);
        a.z = fmaf(xv, w4.z, a.z);
        a.w = fmaf(xv, w4.w, a.w);
      }
    }
  }
  float4 b4 = make_float4(0.f,0.f,0.f,0.f);
  if (BIAS) b4 = *(const float4*)(bias + j0);
  #pragma unroll
  for (int i = 0; i < 16; ++i){
    int n = n0 + r0 + i;
    if (n >= nrows) break;
    float4 v = acc[i];
    if (BIAS){ v.x += b4.x; v.y += b4.y; v.z += b4.z; v.w += b4.w; }
    if (RES){
      float4 rv = *(const float4*)(res + (size_t)n*DD + j0);
      v.x += rv.x; v.y += rv.y; v.z += rv.z; v.w += rv.w;
    }
    if (RELU){ v.x = fmaxf(v.x,0.f); v.y = fmaxf(v.y,0.f); v.z = fmaxf(v.z,0.f); v.w = fmaxf(v.w,0.f); }
    *(float4*)(out + (size_t)n*DD + j0) = v;
  }
}

// ---------------- graph LayerNorm (scalar mean/var over N*D) ----------------
__global__ __launch_bounds__(256) void k_ln_reduce(const float* __restrict__ x, float* __restrict__ pbuf){
  const float4* x4 = (const float4*)x;
  const int n4 = NN*DD/4;
  float s = 0.f, ss = 0.f;
  for (int i = blockIdx.x*256 + threadIdx.x; i < n4; i += gridDim.x*256){
    float4 v = x4[i];
    s  += v.x + v.y + v.z + v.w;
    ss += v.x*v.x + v.y*v.y + v.z*v.z + v.w*v.w;
  }
  #pragma unroll
  for (int m = 32; m >= 1; m >>= 1){ s += __shfl_xor(s, m, 64); ss += __shfl_xor(ss, m, 64); }
  __shared__ float sh[8];
  int wid = threadIdx.x >> 6, lane = threadIdx.x & 63;
  if (lane == 0){ sh[wid*2] = s; sh[wid*2+1] = ss; }
  __syncthreads();
  if (threadIdx.x == 0){
    float S = 0.f, SS = 0.f;
    for (int w = 0; w < 4; ++w){ S += sh[2*w]; SS += sh[2*w+1]; }
    pbuf[blockIdx.x*2] = S; pbuf[blockIdx.x*2+1] = SS;
  }
}

__global__ __launch_bounds__(256) void k_ln_stats(const float* __restrict__ pbuf, float* __restrict__ stats, int nb){
  float s = 0.f, ss = 0.f;
  for (int i = threadIdx.x; i < nb; i += 256){ s += pbuf[2*i]; ss += pbuf[2*i+1]; }
  #pragma unroll
  for (int m = 32; m >= 1; m >>= 1){ s += __shfl_xor(s, m, 64); ss += __shfl_xor(ss, m, 64); }
  __shared__ float sh[8];
  int wid = threadIdx.x >> 6, lane = threadIdx.x & 63;
  if (lane == 0){ sh[wid*2] = s; sh[wid*2+1] = ss; }
  __syncthreads();
  if (threadIdx.x == 0){
    float S = 0.f, SS = 0.f;
    for (int w = 0; w < 4; ++w){ S += sh[2*w]; SS += sh[2*w+1]; }
    const float inv = 1.f/((float)NN*(float)DD);
    float mu = S*inv;
    float var = SS*inv - mu*mu;
    stats[0] = mu;
    stats[1] = rsqrtf(var + 1e-5f);
  }
}

__global__ __launch_bounds__(256) void k_ln_apply(float* __restrict__ x, const float* __restrict__ g,
    const float* __restrict__ be, const float* __restrict__ stats){
  const int n4 = NN*DD/4;
  float mu = stats[0], rs = stats[1];
  float4* x4 = (float4*)x;
  const float4* g4p = (const float4*)g;
  const float4* b4p = (const float4*)be;
  for (int i = blockIdx.x*256 + threadIdx.x; i < n4; i += gridDim.x*256){
    int c4 = i & 31;
    float4 v = x4[i]; float4 gg = g4p[c4]; float4 bb = b4p[c4];
    v.x = (v.x - mu)*rs*gg.x + bb.x;
    v.y = (v.y - mu)*rs*gg.y + bb.y;
    v.z = (v.z - mu)*rs*gg.z + bb.z;
    v.w = (v.w - mu)*rs*gg.w + bb.w;
    x4[i] = v;
  }
}

// ---------------- final projection + segment mean ----------------
__global__ __launch_bounds__(256) void k_final(const float* __restrict__ h, const float* __restrict__ fw,
    const float* __restrict__ fb, const int* __restrict__ batch,
    float* __restrict__ gsum, float* __restrict__ gcnt){
  int n = blockIdx.x*4 + (threadIdx.x >> 6);
  if (n >= NN) return;
  int lane = threadIdx.x & 63;
  const float* r = h + (size_t)n*DD;
  float v = r[lane]*fw[lane] + r[lane+64]*fw[lane+64];
  #pragma unroll
  for (int m = 32; m >= 1; m >>= 1) v += __shfl_xor(v, m, 64);
  if (lane == 0){
    atomicAdd(&gsum[batch[n]], v + fb[0]);
    atomicAdd(&gcnt[batch[n]], 1.f);
  }
}

__global__ void k_out(const float* __restrict__ gsum, const float* __restrict__ gcnt, float* __restrict__ out){
  int g = blockIdx.x*blockDim.x + threadIdx.x;
  if (g < NG) out[g] = gsum[g]/fmaxf(gcnt[g], 1.f);
}

extern "C" void kernel_launch(void* const* d_in, const int* in_sizes, int n_in,
                              void* d_out, int out_size, void* d_ws, size_t ws_size,
                              hipStream_t stream){
  const float* x   = (const float*)d_in[0];
  const int*   ei  = (const int*)d_in[1];
  const int* batch = (const int*)d_in[2];
  const float* W1  = (const float*)d_in[3];
  const float* as1 = (const float*)d_in[4];
  const float* ad1 = (const float*)d_in[5];
  const float* b1  = (const float*)d_in[6];
  const float* W2  = (const float*)d_in[7];
  const float* as2 = (const float*)d_in[8];
  const float* ad2 = (const float*)d_in[9];
  const float* b2  = (const float*)d_in[10];
  const float* fc1w= (const float*)d_in[11];
  const float* fc1b= (const float*)d_in[12];
  const float* fc2w= (const float*)d_in[13];
  const float* fc2b= (const float*)d_in[14];
  const float* fc3w= (const float*)d_in[15];
  const float* fc3b= (const float*)d_in[16];
  const float* fc4w= (const float*)d_in[17];
  const float* fc4b= (const float*)d_in[18];
  const float* g1  = (const float*)d_in[19];
  const float* be1 = (const float*)d_in[20];
  const float* g2  = (const float*)d_in[21];
  const float* be2 = (const float*)d_in[22];
  const float* fcw = (const float*)d_in[23];
  const float* fcb = (const float*)d_in[24];
  float* out = (float*)d_out;
  (void)in_sizes; (void)n_in; (void)out_size; (void)ws_size;

  char* ws = (char*)d_ws;
  size_t off = 0;
  auto alloc = [&](size_t bytes)->void*{
    void* p = ws + off;
    off += (bytes + 255) & ~(size_t)255;
    return p;
  };
  float* A    = (float*)alloc((size_t)NN*DD*4);
  float* B    = (float*)alloc((size_t)NN*DD*4);
  float* C    = (float*)alloc((size_t)NN*DD*4);
  float* als1 = (float*)alloc((size_t)NN*NH*4);
  float* ald1 = (float*)alloc((size_t)NN*NH*4);
  float* als2 = (float*)alloc((size_t)NN*4);
  float* ald2 = (float*)alloc((size_t)NN*4);
  int*   cnt    = (int*)alloc((size_t)NN*4);
  int*   rowptr = (int*)alloc((size_t)(NN+1)*4);
  int*   wo     = (int*)alloc((size_t)NN*4);
  int*   col    = (int*)alloc((size_t)NE*4);
  int*   ipart  = (int*)alloc(256*4);
  float* pbuf   = (float*)alloc(1024*2*4);
  float* stats  = (float*)alloc(2*4);
  float* gsum   = (float*)alloc(NG*4);
  float* gcnt   = (float*)alloc(NG*4);

  const int* esrc = ei;
  const int* edst = ei + NE;

  hipMemsetAsync(cnt, 0, (size_t)NN*4, stream);
  hipMemsetAsync(gsum, 0, NG*4, stream);
  hipMemsetAsync(gcnt, 0, NG*4, stream);

  // CSR by dst (self-loops handled analytically in aggregation)
  k_count<<<(NE+255)/256, 256, 0, stream>>>(edst, cnt);
  const int NB1 = (NN + 511)/512;
  k_scan1<<<NB1, 512, 0, stream>>>(cnt, rowptr, ipart);
  k_scan2<<<1, 256, 0, stream>>>(ipart, NB1);
  k_scan3<<<NB1, 512, 0, stream>>>(rowptr, wo, ipart, cnt);
  k_fill<<<(NE+255)/256, 256, 0, stream>>>(esrc, edst, wo, col);

  // GAT layer 1
  k_lin1<<<NN, 128, 0, stream>>>(x, W1, as1, ad1, A, als1, ald1);
  k_gat1<<<NN, 128, 0, stream>>>(A, als1, ald1, rowptr, col, b1, B);

  const int GB = (NN + 127)/128;
  // fc1 (relu), fc2 (+res h1, relu)
  k_gemm128<true,  true, false><<<GB, 256, 0, stream>>>(B, fc1w, fc1b, nullptr, A, NN);
  k_gemm128<true,  true, true ><<<GB, 256, 0, stream>>>(A, fc2w, fc2b, B,       C, NN);

  // LN1 (graph mode)
  k_ln_reduce<<<1024, 256, 0, stream>>>(C, pbuf);
  k_ln_stats<<<1, 256, 0, stream>>>(pbuf, stats, 1024);
  k_ln_apply<<<1024, 256, 0, stream>>>(C, g1, be1, stats);

  // GAT layer 2 (t2 = C @ W2)
  k_gemm128<false, false, false><<<GB, 256, 0, stream>>>(C, W2, nullptr, nullptr, A, NN);
  k_al2<<<(NN+3)/4, 256, 0, stream>>>(A, as2, ad2, als2, ald2);
  k_gat2<<<NN, 128, 0, stream>>>(A, als2, ald2, rowptr, col, b2, B);

  // fc3 (relu), fc4 (+res C, no relu)
  k_gemm128<true,  true, false><<<GB, 256, 0, stream>>>(B, fc3w, fc3b, nullptr, A, NN);
  k_gemm128<false, true, true ><<<GB, 256, 0, stream>>>(A, fc4w, fc4b, C,       B, NN);

  // LN2
  k_ln_reduce<<<1024, 256, 0, stream>>>(B, pbuf);
  k_ln_stats<<<1, 256, 0, stream>>>(pbuf, stats, 1024);
  k_ln_apply<<<1024, 256, 0, stream>>>(B, g2, be2, stats);

  // final projection + global mean pool per graph
  k_final<<<(NN+3)/4, 256, 0, stream>>>(B, fcw, fcb, batch, gsum, gcnt);
  k_out<<<(NG+255)/256, 256, 0, stream>>>(gsum, gcnt, out);
}

// Round 2
// 1200.467 us; speedup vs baseline: 1.1145x; 1.1145x over previous
//
#include <hip/hip_runtime.h>
#include <cstdint>

#define NN 100000
#define NE 1600000
#define DI 9
#define DD 128
#define NH 8
#define NG 1000

__device__ __forceinline__ float leaky(float x){ return x > 0.f ? x : 0.2f*x; }

// ---------------- CSR build ----------------
__global__ void k_count(const int* __restrict__ dst, int* __restrict__ cnt){
  int i = blockIdx.x*blockDim.x + threadIdx.x;
  if (i < NE) atomicAdd(&cnt[dst[i]], 1);
}

__global__ __launch_bounds__(512) void k_scan1(const int* __restrict__ cnt, int* __restrict__ rowptr,
                                               int* __restrict__ partial){
  __shared__ int sh[512];
  int tid = threadIdx.x;
  int i = blockIdx.x*512 + tid;
  int v = (i < NN) ? cnt[i] : 0;
  sh[tid] = v;
  __syncthreads();
  for (int off = 1; off < 512; off <<= 1){
    int t = (tid >= off) ? sh[tid-off] : 0;
    __syncthreads();
    sh[tid] += t;
    __syncthreads();
  }
  if (i < NN) rowptr[i] = sh[tid] - v;          // exclusive
  if (tid == 511) partial[blockIdx.x] = sh[511]; // block total
}

__global__ __launch_bounds__(256) void k_scan2(int* partial, int nb){
  __shared__ int sh[256];
  int tid = threadIdx.x;
  int v = (tid < nb) ? partial[tid] : 0;
  sh[tid] = v;
  __syncthreads();
  for (int off = 1; off < 256; off <<= 1){
    int t = (tid >= off) ? sh[tid-off] : 0;
    __syncthreads();
    sh[tid] += t;
    __syncthreads();
  }
  if (tid < nb) partial[tid] = sh[tid] - v;      // exclusive
}

__global__ __launch_bounds__(512) void k_scan3(int* __restrict__ rowptr, int* __restrict__ wo,
                                               const int* __restrict__ partial, const int* __restrict__ cnt){
  int i = blockIdx.x*512 + threadIdx.x;
  if (i < NN){
    int v = rowptr[i] + partial[blockIdx.x];
    rowptr[i] = v;
    wo[i] = v;
    if (i == NN-1) rowptr[NN] = v + cnt[i];
  }
}

__global__ void k_fill(const int* __restrict__ src, const int* __restrict__ dst,
                       int* __restrict__ wo, int* __restrict__ col){
  int i = blockIdx.x*blockDim.x + threadIdx.x;
  if (i < NE){
    int p = atomicAdd(&wo[dst[i]], 1);
    col[p] = src[i];
  }
}

// ---------------- GAT1 linear (x@W1) + attention logits ----------------
__global__ __launch_bounds__(128) void k_lin1(const float* __restrict__ x, const float* __restrict__ W1,
    const float* __restrict__ as1, const float* __restrict__ ad1,
    float* __restrict__ t1, float* __restrict__ al_s, float* __restrict__ al_d){
  int n = blockIdx.x;
  int c = threadIdx.x;
  const float* xr = x + n*DI;
  float t = 0.f;
  #pragma unroll
  for (int k = 0; k < DI; ++k) t = fmaf(xr[k], W1[k*DD+c], t);
  t1[(size_t)n*DD + c] = t;
  float vs = t * as1[c];
  float vd = t * ad1[c];
  #pragma unroll
  for (int m = 8; m >= 1; m >>= 1){ vs += __shfl_xor(vs, m, 16); vd += __shfl_xor(vd, m, 16); }
  if ((c & 15) == 0){
    al_s[n*NH + (c>>4)] = vs;
    al_d[n*NH + (c>>4)] = vd;
  }
}

// ---------------- attn coeffs layer 1: wave per node, 8 edges x 8 heads per chunk ----------------
__global__ __launch_bounds__(256) void k_attn1(const float* __restrict__ al_s, const float* __restrict__ al_d,
    const int* __restrict__ rowptr, const int* __restrict__ col,
    float* __restrict__ alpha, float* __restrict__ a0n, float* __restrict__ invden){
  int n = blockIdx.x*4 + (threadIdx.x >> 6);
  if (n >= NN) return;
  int lane = threadIdx.x & 63;
  int h = lane & 7, j = lane >> 3;
  int beg = rowptr[n], end = rowptr[n+1];
  float ald = al_d[n*NH + h];
  float es = leaky(al_s[n*NH + h] + ald);       // self-loop
  float vmax = -3.4e38f;
  for (int e = beg + j; e < end; e += 8){
    int s = col[e];
    vmax = fmaxf(vmax, leaky(al_s[s*NH + h] + ald));
  }
  vmax = fmaxf(vmax, __shfl_xor(vmax, 8, 64));
  vmax = fmaxf(vmax, __shfl_xor(vmax, 16, 64));
  vmax = fmaxf(vmax, __shfl_xor(vmax, 32, 64));
  float m = fmaxf(es, vmax);
  float sl = 0.f;
  for (int e = beg + j; e < end; e += 8){
    int s = col[e];
    float a = __expf(leaky(al_s[s*NH + h] + ald) - m);
    alpha[(size_t)e*NH + h] = a;                // 64 consecutive floats per chunk
    sl += a;
  }
  sl += __shfl_xor(sl, 8, 64);
  sl += __shfl_xor(sl, 16, 64);
  sl += __shfl_xor(sl, 32, 64);
  float a0 = __expf(es - m);
  float inv = 1.f/(a0 + sl + 1e-16f);
  if (j == 0){
    a0n[n*NH + h]    = a0*inv;
    invden[n*NH + h] = inv;
  }
}

// ---------------- GAT1 gather: single pass, unrolled x4, + b1, ReLU ----------------
__global__ __launch_bounds__(128) void k_gat1g(const float* __restrict__ t1,
    const float* __restrict__ alpha, const float* __restrict__ a0n, const float* __restrict__ invden,
    const int* __restrict__ rowptr, const int* __restrict__ col,
    const float* __restrict__ b1, float* __restrict__ out){
  int n = blockIdx.x, c = threadIdx.x, h = c >> 4;
  int beg = rowptr[n], end = rowptr[n+1];
  float sum = 0.f;
  int e = beg;
  for (; e + 4 <= end; e += 4){
    int s0 = col[e], s1 = col[e+1], s2 = col[e+2], s3 = col[e+3];
    float a0_ = alpha[(size_t)e*NH + h];
    float a1_ = alpha[(size_t)(e+1)*NH + h];
    float a2_ = alpha[(size_t)(e+2)*NH + h];
    float a3_ = alpha[(size_t)(e+3)*NH + h];
    float v0 = t1[(size_t)s0*DD + c];
    float v1 = t1[(size_t)s1*DD + c];
    float v2 = t1[(size_t)s2*DD + c];
    float v3 = t1[(size_t)s3*DD + c];
    sum = fmaf(a0_, v0, sum); sum = fmaf(a1_, v1, sum);
    sum = fmaf(a2_, v2, sum); sum = fmaf(a3_, v3, sum);
  }
  for (; e < end; ++e)
    sum = fmaf(alpha[(size_t)e*NH + h], t1[(size_t)col[e]*DD + c], sum);
  float v = fmaf(invden[n*NH + h], sum, a0n[n*NH + h]*t1[(size_t)n*DD + c]) + b1[c];
  out[(size_t)n*DD + c] = fmaxf(v, 0.f);
}

// ---------------- GAT2 attention logits (1 head over 128 ch) ----------------
__global__ __launch_bounds__(256) void k_al2(const float* __restrict__ t2,
    const float* __restrict__ as2, const float* __restrict__ ad2,
    float* __restrict__ al_s, float* __restrict__ al_d){
  int n = blockIdx.x*4 + (threadIdx.x >> 6);
  if (n >= NN) return;
  int lane = threadIdx.x & 63;
  const float* r = t2 + (size_t)n*DD;
  float vs = r[lane]*as2[lane] + r[lane+64]*as2[lane+64];
  float vd = r[lane]*ad2[lane] + r[lane+64]*ad2[lane+64];
  #pragma unroll
  for (int m = 32; m >= 1; m >>= 1){ vs += __shfl_xor(vs, m, 64); vd += __shfl_xor(vd, m, 64); }
  if (lane == 0){ al_s[n] = vs; al_d[n] = vd; }
}

// ---------------- attn coeffs layer 2: wave per node, 64 edges per chunk ----------------
__global__ __launch_bounds__(256) void k_attn2(const float* __restrict__ al_s, const float* __restrict__ al_d,
    const int* __restrict__ rowptr, const int* __restrict__ col,
    float* __restrict__ alpha, float* __restrict__ a0n, float* __restrict__ invden){
  int n = blockIdx.x*4 + (threadIdx.x >> 6);
  if (n >= NN) return;
  int lane = threadIdx.x & 63;
  int beg = rowptr[n], end = rowptr[n+1];
  float ald = al_d[n];
  float es = leaky(al_s[n] + ald);
  float vmax = -3.4e38f;
  for (int e = beg + lane; e < end; e += 64)
    vmax = fmaxf(vmax, leaky(al_s[col[e]] + ald));
  #pragma unroll
  for (int mk = 32; mk >= 1; mk >>= 1) vmax = fmaxf(vmax, __shfl_xor(vmax, mk, 64));
  float m = fmaxf(es, vmax);
  float sl = 0.f;
  for (int e = beg + lane; e < end; e += 64){
    float a = __expf(leaky(al_s[col[e]] + ald) - m);
    alpha[e] = a;
    sl += a;
  }
  #pragma unroll
  for (int mk = 32; mk >= 1; mk >>= 1) sl += __shfl_xor(sl, mk, 64);
  float a0 = __expf(es - m);
  float inv = 1.f/(a0 + sl + 1e-16f);
  if (lane == 0){ a0n[n] = a0*inv; invden[n] = inv; }
}

// ---------------- GAT2 gather: single pass, unrolled x4, + b2 ----------------
__global__ __launch_bounds__(128) void k_gat2g(const float* __restrict__ t2,
    const float* __restrict__ alpha, const float* __restrict__ a0n, const float* __restrict__ invden,
    const int* __restrict__ rowptr, const int* __restrict__ col,
    const float* __restrict__ b2, float* __restrict__ out){
  int n = blockIdx.x, c = threadIdx.x;
  int beg = rowptr[n], end = rowptr[n+1];
  float sum = 0.f;
  int e = beg;
  for (; e + 4 <= end; e += 4){
    int s0 = col[e], s1 = col[e+1], s2 = col[e+2], s3 = col[e+3];
    float a0_ = alpha[e],   a1_ = alpha[e+1];
    float a2_ = alpha[e+2], a3_ = alpha[e+3];
    float v0 = t2[(size_t)s0*DD + c];
    float v1 = t2[(size_t)s1*DD + c];
    float v2 = t2[(size_t)s2*DD + c];
    float v3 = t2[(size_t)s3*DD + c];
    sum = fmaf(a0_, v0, sum); sum = fmaf(a1_, v1, sum);
    sum = fmaf(a2_, v2, sum); sum = fmaf(a3_, v3, sum);
  }
  for (; e < end; ++e)
    sum = fmaf(alpha[e], t2[(size_t)col[e]*DD + c], sum);
  out[(size_t)n*DD + c] = fmaf(invden[n], sum, a0n[n]*t2[(size_t)n*DD + c]) + b2[c];
}

// ---------------- 128x128 GEMM, register-tiled, optional bias/res/relu ----------------
template<bool RELU, bool BIAS, bool RES>
__global__ __launch_bounds__(256) void k_gemm128(const float* __restrict__ X, const float* __restrict__ W,
    const float* __restrict__ bias, const float* __restrict__ res, float* __restrict__ out, int nrows){
  __shared__ __align__(16) float Xs[DD][132];   // [k][r], padded rows
  int tid = threadIdx.x;
  int n0 = blockIdx.x * 128;
  {
    int r  = tid >> 1;
    int c0 = (tid & 1) * 64;
    int n  = n0 + r;
    if (n < nrows){
      const float* xp = X + (size_t)n*DD + c0;
      #pragma unroll
      for (int i = 0; i < 16; ++i){
        float4 v = *(const float4*)(xp + i*4);
        int c = c0 + i*4;
        Xs[c][r] = v.x; Xs[c+1][r] = v.y; Xs[c+2][r] = v.z; Xs[c+3][r] = v.w;
      }
    } else {
      #pragma unroll
      for (int i = 0; i < 16; ++i){
        int c = c0 + i*4;
        Xs[c][r] = 0.f; Xs[c+1][r] = 0.f; Xs[c+2][r] = 0.f; Xs[c+3][r] = 0.f;
      }
    }
  }
  __syncthreads();
  int tc = tid & 31, tr = tid >> 5;
  int j0 = tc*4, r0 = tr*16;
  float4 acc[16];
  #pragma unroll
  for (int i = 0; i < 16; ++i) acc[i] = make_float4(0.f,0.f,0.f,0.f);
  #pragma unroll 2
  for (int k = 0; k < DD; ++k){
    float4 w4 = *(const float4*)(W + k*DD + j0);
    #pragma unroll
    for (int ii = 0; ii < 4; ++ii){
      float4 x4 = *(const float4*)&Xs[k][r0 + ii*4];
      float xs[4] = {x4.x, x4.y, x4.z, x4.w};
      #pragma unroll
      for (int jj = 0; jj < 4; ++jj){
        float xv = xs[jj];
        float4& a = acc[ii*4+jj];
        a.x = fmaf(xv, w4.x, a.x);
        a.y = fmaf(xv, w4.y, a.y);
        a.z = fmaf(xv, w4.z, a.z);
        a.w = fmaf(xv, w4.w, a.w);
      }
    }
  }
  float4 b4 = make_float4(0.f,0.f,0.f,0.f);
  if (BIAS) b4 = *(const float4*)(bias + j0);
  #pragma unroll
  for (int i = 0; i < 16; ++i){
    int n = n0 + r0 + i;
    if (n >= nrows) break;
    float4 v = acc[i];
    if (BIAS){ v.x += b4.x; v.y += b4.y; v.z += b4.z; v.w += b4.w; }
    if (RES){
      float4 rv = *(const float4*)(res + (size_t)n*DD + j0);
      v.x += rv.x; v.y += rv.y; v.z += rv.z; v.w += rv.w;
    }
    if (RELU){ v.x = fmaxf(v.x,0.f); v.y = fmaxf(v.y,0.f); v.z = fmaxf(v.z,0.f); v.w = fmaxf(v.w,0.f); }
    *(float4*)(out + (size_t)n*DD + j0) = v;
  }
}

// ---------------- graph LayerNorm (scalar mean/var over N*D) ----------------
__global__ __launch_bounds__(256) void k_ln_reduce(const float* __restrict__ x, float* __restrict__ pbuf){
  const float4* x4 = (const float4*)x;
  const int n4 = NN*DD/4;
  float s = 0.f, ss = 0.f;
  for (int i = blockIdx.x*256 + threadIdx.x; i < n4; i += gridDim.x*256){
    float4 v = x4[i];
    s  += v.x + v.y + v.z + v.w;
    ss += v.x*v.x + v.y*v.y + v.z*v.z + v.w*v.w;
  }
  #pragma unroll
  for (int m = 32; m >= 1; m >>= 1){ s += __shfl_xor(s, m, 64); ss += __shfl_xor(ss, m, 64); }
  __shared__ float sh[8];
  int wid = threadIdx.x >> 6, lane = threadIdx.x & 63;
  if (lane == 0){ sh[wid*2] = s; sh[wid*2+1] = ss; }
  __syncthreads();
  if (threadIdx.x == 0){
    float S = 0.f, SS = 0.f;
    for (int w = 0; w < 4; ++w){ S += sh[2*w]; SS += sh[2*w+1]; }
    pbuf[blockIdx.x*2] = S; pbuf[blockIdx.x*2+1] = SS;
  }
}

__global__ __launch_bounds__(256) void k_ln_stats(const float* __restrict__ pbuf, float* __restrict__ stats, int nb){
  float s = 0.f, ss = 0.f;
  for (int i = threadIdx.x; i < nb; i += 256){ s += pbuf[2*i]; ss += pbuf[2*i+1]; }
  #pragma unroll
  for (int m = 32; m >= 1; m >>= 1){ s += __shfl_xor(s, m, 64); ss += __shfl_xor(ss, m, 64); }
  __shared__ float sh[8];
  int wid = threadIdx.x >> 6, lane = threadIdx.x & 63;
  if (lane == 0){ sh[wid*2] = s; sh[wid*2+1] = ss; }
  __syncthreads();
  if (threadIdx.x == 0){
    float S = 0.f, SS = 0.f;
    for (int w = 0; w < 4; ++w){ S += sh[2*w]; SS += sh[2*w+1]; }
    const float inv = 1.f/((float)NN*(float)DD);
    float mu = S*inv;
    float var = SS*inv - mu*mu;
    stats[0] = mu;
    stats[1] = rsqrtf(var + 1e-5f);
  }
}

__global__ __launch_bounds__(256) void k_ln_apply(float* __restrict__ x, const float* __restrict__ g,
    const float* __restrict__ be, const float* __restrict__ stats){
  const int n4 = NN*DD/4;
  float mu = stats[0], rs = stats[1];
  float4* x4 = (float4*)x;
  const float4* g4p = (const float4*)g;
  const float4* b4p = (const float4*)be;
  for (int i = blockIdx.x*256 + threadIdx.x; i < n4; i += gridDim.x*256){
    int c4 = i & 31;
    float4 v = x4[i]; float4 gg = g4p[c4]; float4 bb = b4p[c4];
    v.x = (v.x - mu)*rs*gg.x + bb.x;
    v.y = (v.y - mu)*rs*gg.y + bb.y;
    v.z = (v.z - mu)*rs*gg.z + bb.z;
    v.w = (v.w - mu)*rs*gg.w + bb.w;
    x4[i] = v;
  }
}

// ---------------- final projection + segment mean ----------------
__global__ __launch_bounds__(256) void k_final(const float* __restrict__ h, const float* __restrict__ fw,
    const float* __restrict__ fb, const int* __restrict__ batch,
    float* __restrict__ gsum, float* __restrict__ gcnt){
  int n = blockIdx.x*4 + (threadIdx.x >> 6);
  if (n >= NN) return;
  int lane = threadIdx.x & 63;
  const float* r = h + (size_t)n*DD;
  float v = r[lane]*fw[lane] + r[lane+64]*fw[lane+64];
  #pragma unroll
  for (int m = 32; m >= 1; m >>= 1) v += __shfl_xor(v, m, 64);
  if (lane == 0){
    atomicAdd(&gsum[batch[n]], v + fb[0]);
    atomicAdd(&gcnt[batch[n]], 1.f);
  }
}

__global__ void k_out(const float* __restrict__ gsum, const float* __restrict__ gcnt, float* __restrict__ out){
  int g = blockIdx.x*blockDim.x + threadIdx.x;
  if (g < NG) out[g] = gsum[g]/fmaxf(gcnt[g], 1.f);
}

extern "C" void kernel_launch(void* const* d_in, const int* in_sizes, int n_in,
                              void* d_out, int out_size, void* d_ws, size_t ws_size,
                              hipStream_t stream){
  const float* x   = (const float*)d_in[0];
  const int*   ei  = (const int*)d_in[1];
  const int* batch = (const int*)d_in[2];
  const float* W1  = (const float*)d_in[3];
  const float* as1 = (const float*)d_in[4];
  const float* ad1 = (const float*)d_in[5];
  const float* b1  = (const float*)d_in[6];
  const float* W2  = (const float*)d_in[7];
  const float* as2 = (const float*)d_in[8];
  const float* ad2 = (const float*)d_in[9];
  const float* b2  = (const float*)d_in[10];
  const float* fc1w= (const float*)d_in[11];
  const float* fc1b= (const float*)d_in[12];
  const float* fc2w= (const float*)d_in[13];
  const float* fc2b= (const float*)d_in[14];
  const float* fc3w= (const float*)d_in[15];
  const float* fc3b= (const float*)d_in[16];
  const float* fc4w= (const float*)d_in[17];
  const float* fc4b= (const float*)d_in[18];
  const float* g1  = (const float*)d_in[19];
  const float* be1 = (const float*)d_in[20];
  const float* g2  = (const float*)d_in[21];
  const float* be2 = (const float*)d_in[22];
  const float* fcw = (const float*)d_in[23];
  const float* fcb = (const float*)d_in[24];
  float* out = (float*)d_out;
  (void)in_sizes; (void)n_in; (void)out_size; (void)ws_size;

  char* ws = (char*)d_ws;
  size_t off = 0;
  auto alloc = [&](size_t bytes)->void*{
    void* p = ws + off;
    off += (bytes + 255) & ~(size_t)255;
    return p;
  };
  float* A    = (float*)alloc((size_t)NN*DD*4);
  float* B    = (float*)alloc((size_t)NN*DD*4);
  float* C    = (float*)alloc((size_t)NN*DD*4);   // doubles as alpha1 [E,8] (12.8M floats) during layer-1 GAT
  float* als1 = (float*)alloc((size_t)NN*NH*4);
  float* ald1 = (float*)alloc((size_t)NN*NH*4);
  float* a0n1 = (float*)alloc((size_t)NN*NH*4);
  float* inv1 = (float*)alloc((size_t)NN*NH*4);
  float* als2 = (float*)alloc((size_t)NN*4);
  float* ald2 = (float*)alloc((size_t)NN*4);
  float* a0n2 = (float*)alloc((size_t)NN*4);
  float* inv2 = (float*)alloc((size_t)NN*4);
  float* alpha2 = (float*)alloc((size_t)NE*4);
  int*   cnt    = (int*)alloc((size_t)NN*4);
  int*   rowptr = (int*)alloc((size_t)(NN+1)*4);
  int*   wo     = (int*)alloc((size_t)NN*4);
  int*   col    = (int*)alloc((size_t)NE*4);
  int*   ipart  = (int*)alloc(256*4);
  float* pbuf   = (float*)alloc(1024*2*4);
  float* stats  = (float*)alloc(2*4);
  float* gsum   = (float*)alloc(NG*4);
  float* gcnt   = (float*)alloc(NG*4);

  float* alpha1 = C;   // alias: C is dead until fc2 output

  const int* esrc = ei;
  const int* edst = ei + NE;

  hipMemsetAsync(cnt, 0, (size_t)NN*4, stream);
  hipMemsetAsync(gsum, 0, NG*4, stream);
  hipMemsetAsync(gcnt, 0, NG*4, stream);

  // CSR by dst (self-loops handled analytically in aggregation)
  k_count<<<(NE+255)/256, 256, 0, stream>>>(edst, cnt);
  const int NB1 = (NN + 511)/512;
  k_scan1<<<NB1, 512, 0, stream>>>(cnt, rowptr, ipart);
  k_scan2<<<1, 256, 0, stream>>>(ipart, NB1);
  k_scan3<<<NB1, 512, 0, stream>>>(rowptr, wo, ipart, cnt);
  k_fill<<<(NE+255)/256, 256, 0, stream>>>(esrc, edst, wo, col);

  const int WB = (NN + 3)/4;   // wave-per-node kernels, 4 waves/block

  // GAT layer 1
  k_lin1<<<NN, 128, 0, stream>>>(x, W1, as1, ad1, A, als1, ald1);
  k_attn1<<<WB, 256, 0, stream>>>(als1, ald1, rowptr, col, alpha1, a0n1, inv1);
  k_gat1g<<<NN, 128, 0, stream>>>(A, alpha1, a0n1, inv1, rowptr, col, b1, B);

  const int GB = (NN + 127)/128;
  // fc1 (relu), fc2 (+res h1, relu)
  k_gemm128<true,  true, false><<<GB, 256, 0, stream>>>(B, fc1w, fc1b, nullptr, A, NN);
  k_gemm128<true,  true, true ><<<GB, 256, 0, stream>>>(A, fc2w, fc2b, B,       C, NN);

  // LN1 (graph mode)
  k_ln_reduce<<<1024, 256, 0, stream>>>(C, pbuf);
  k_ln_stats<<<1, 256, 0, stream>>>(pbuf, stats, 1024);
  k_ln_apply<<<1024, 256, 0, stream>>>(C, g1, be1, stats);

  // GAT layer 2 (t2 = C @ W2)
  k_gemm128<false, false, false><<<GB, 256, 0, stream>>>(C, W2, nullptr, nullptr, A, NN);
  k_al2<<<WB, 256, 0, stream>>>(A, as2, ad2, als2, ald2);
  k_attn2<<<WB, 256, 0, stream>>>(als2, ald2, rowptr, col, alpha2, a0n2, inv2);
  k_gat2g<<<NN, 128, 0, stream>>>(A, alpha2, a0n2, inv2, rowptr, col, b2, B);

  // fc3 (relu), fc4 (+res C, no relu)
  k_gemm128<true,  true, false><<<GB, 256, 0, stream>>>(B, fc3w, fc3b, nullptr, A, NN);
  k_gemm128<false, true, true ><<<GB, 256, 0, stream>>>(A, fc4w, fc4b, C,       B, NN);

  // LN2
  k_ln_reduce<<<1024, 256, 0, stream>>>(B, pbuf);
  k_ln_stats<<<1, 256, 0, stream>>>(pbuf, stats, 1024);
  k_ln_apply<<<1024, 256, 0, stream>>>(B, g2, be2, stats);

  // final projection + global mean pool per graph
  k_final<<<WB, 256, 0, stream>>>(B, fcw, fcb, batch, gsum, gcnt);
  k_out<<<(NG+255)/256, 256, 0, stream>>>(gsum, gcnt, out);
}

// Round 3
// 1002.383 us; speedup vs baseline: 1.3348x; 1.1976x over previous
//
#include <hip/hip_runtime.h>
#include <cstdint>

#define NN 100000
#define NE 1600000
#define DI 9
#define DD 128
#define NH 8
#define NG 1000

__device__ __forceinline__ float leaky(float x){ return x > 0.f ? x : 0.2f*x; }

// ---------------- CSR build ----------------
__global__ void k_count(const int* __restrict__ dst, int* __restrict__ cnt){
  int i = blockIdx.x*blockDim.x + threadIdx.x;
  if (i < NE) atomicAdd(&cnt[dst[i]], 1);
}

__global__ __launch_bounds__(512) void k_scan1(const int* __restrict__ cnt, int* __restrict__ rowptr,
                                               int* __restrict__ partial){
  __shared__ int sh[512];
  int tid = threadIdx.x;
  int i = blockIdx.x*512 + tid;
  int v = (i < NN) ? cnt[i] : 0;
  sh[tid] = v;
  __syncthreads();
  for (int off = 1; off < 512; off <<= 1){
    int t = (tid >= off) ? sh[tid-off] : 0;
    __syncthreads();
    sh[tid] += t;
    __syncthreads();
  }
  if (i < NN) rowptr[i] = sh[tid] - v;          // exclusive
  if (tid == 511) partial[blockIdx.x] = sh[511]; // block total
}

__global__ __launch_bounds__(256) void k_scan2(int* partial, int nb){
  __shared__ int sh[256];
  int tid = threadIdx.x;
  int v = (tid < nb) ? partial[tid] : 0;
  sh[tid] = v;
  __syncthreads();
  for (int off = 1; off < 256; off <<= 1){
    int t = (tid >= off) ? sh[tid-off] : 0;
    __syncthreads();
    sh[tid] += t;
    __syncthreads();
  }
  if (tid < nb) partial[tid] = sh[tid] - v;      // exclusive
}

__global__ __launch_bounds__(512) void k_scan3(int* __restrict__ rowptr, int* __restrict__ wo,
                                               const int* __restrict__ partial, const int* __restrict__ cnt){
  int i = blockIdx.x*512 + threadIdx.x;
  if (i < NN){
    int v = rowptr[i] + partial[blockIdx.x];
    rowptr[i] = v;
    wo[i] = v;
    if (i == NN-1) rowptr[NN] = v + cnt[i];
  }
}

__global__ void k_fill(const int* __restrict__ src, const int* __restrict__ dst,
                       int* __restrict__ wo, int* __restrict__ col){
  int i = blockIdx.x*blockDim.x + threadIdx.x;
  if (i < NE){
    int p = atomicAdd(&wo[dst[i]], 1);
    col[p] = src[i];
  }
}

// ---------------- GAT1 linear (x@W1) + attention logits ----------------
__global__ __launch_bounds__(128) void k_lin1(const float* __restrict__ x, const float* __restrict__ W1,
    const float* __restrict__ as1, const float* __restrict__ ad1,
    float* __restrict__ t1, float* __restrict__ al_s, float* __restrict__ al_d){
  int n = blockIdx.x;
  int c = threadIdx.x;
  const float* xr = x + n*DI;
  float t = 0.f;
  #pragma unroll
  for (int k = 0; k < DI; ++k) t = fmaf(xr[k], W1[k*DD+c], t);
  t1[(size_t)n*DD + c] = t;
  float vs = t * as1[c];
  float vd = t * ad1[c];
  #pragma unroll
  for (int m = 8; m >= 1; m >>= 1){ vs += __shfl_xor(vs, m, 16); vd += __shfl_xor(vd, m, 16); }
  if ((c & 15) == 0){
    al_s[n*NH + (c>>4)] = vs;
    al_d[n*NH + (c>>4)] = vd;
  }
}

// ---------------- attn coeffs layer 1: wave per node, 8 edges x 8 heads per chunk ----------------
__global__ __launch_bounds__(256) void k_attn1(const float* __restrict__ al_s, const float* __restrict__ al_d,
    const int* __restrict__ rowptr, const int* __restrict__ col,
    float* __restrict__ alpha, float* __restrict__ a0n, float* __restrict__ invden){
  int n = blockIdx.x*4 + (threadIdx.x >> 6);
  if (n >= NN) return;
  int lane = threadIdx.x & 63;
  int h = lane & 7, j = lane >> 3;
  int beg = rowptr[n], end = rowptr[n+1];
  float ald = al_d[n*NH + h];
  float es = leaky(al_s[n*NH + h] + ald);       // self-loop
  float vmax = -3.4e38f;
  for (int e = beg + j; e < end; e += 8){
    int s = col[e];
    vmax = fmaxf(vmax, leaky(al_s[s*NH + h] + ald));
  }
  vmax = fmaxf(vmax, __shfl_xor(vmax, 8, 64));
  vmax = fmaxf(vmax, __shfl_xor(vmax, 16, 64));
  vmax = fmaxf(vmax, __shfl_xor(vmax, 32, 64));
  float m = fmaxf(es, vmax);
  float sl = 0.f;
  for (int e = beg + j; e < end; e += 8){
    int s = col[e];
    float a = __expf(leaky(al_s[s*NH + h] + ald) - m);
    alpha[(size_t)e*NH + h] = a;                // 64 consecutive floats per chunk
    sl += a;
  }
  sl += __shfl_xor(sl, 8, 64);
  sl += __shfl_xor(sl, 16, 64);
  sl += __shfl_xor(sl, 32, 64);
  float a0 = __expf(es - m);
  float inv = 1.f/(a0 + sl + 1e-16f);
  if (j == 0){
    a0n[n*NH + h]    = a0*inv;
    invden[n*NH + h] = inv;
  }
}

// ---------------- GAT1 gather: single pass, unrolled x4, + b1, ReLU ----------------
__global__ __launch_bounds__(128) void k_gat1g(const float* __restrict__ t1,
    const float* __restrict__ alpha, const float* __restrict__ a0n, const float* __restrict__ invden,
    const int* __restrict__ rowptr, const int* __restrict__ col,
    const float* __restrict__ b1, float* __restrict__ out){
  int n = blockIdx.x, c = threadIdx.x, h = c >> 4;
  int beg = rowptr[n], end = rowptr[n+1];
  float sum = 0.f;
  int e = beg;
  for (; e + 4 <= end; e += 4){
    int s0 = col[e], s1 = col[e+1], s2 = col[e+2], s3 = col[e+3];
    float a0_ = alpha[(size_t)e*NH + h];
    float a1_ = alpha[(size_t)(e+1)*NH + h];
    float a2_ = alpha[(size_t)(e+2)*NH + h];
    float a3_ = alpha[(size_t)(e+3)*NH + h];
    float v0 = t1[(size_t)s0*DD + c];
    float v1 = t1[(size_t)s1*DD + c];
    float v2 = t1[(size_t)s2*DD + c];
    float v3 = t1[(size_t)s3*DD + c];
    sum = fmaf(a0_, v0, sum); sum = fmaf(a1_, v1, sum);
    sum = fmaf(a2_, v2, sum); sum = fmaf(a3_, v3, sum);
  }
  for (; e < end; ++e)
    sum = fmaf(alpha[(size_t)e*NH + h], t1[(size_t)col[e]*DD + c], sum);
  float v = fmaf(invden[n*NH + h], sum, a0n[n*NH + h]*t1[(size_t)n*DD + c]) + b1[c];
  out[(size_t)n*DD + c] = fmaxf(v, 0.f);
}

// ---------------- GAT2 attention logits (1 head over 128 ch) ----------------
__global__ __launch_bounds__(256) void k_al2(const float* __restrict__ t2,
    const float* __restrict__ as2, const float* __restrict__ ad2,
    float* __restrict__ al_s, float* __restrict__ al_d){
  int n = blockIdx.x*4 + (threadIdx.x >> 6);
  if (n >= NN) return;
  int lane = threadIdx.x & 63;
  const float* r = t2 + (size_t)n*DD;
  float vs = r[lane]*as2[lane] + r[lane+64]*as2[lane+64];
  float vd = r[lane]*ad2[lane] + r[lane+64]*ad2[lane+64];
  #pragma unroll
  for (int m = 32; m >= 1; m >>= 1){ vs += __shfl_xor(vs, m, 64); vd += __shfl_xor(vd, m, 64); }
  if (lane == 0){ al_s[n] = vs; al_d[n] = vd; }
}

// ---------------- attn coeffs layer 2: wave per node, 64 edges per chunk ----------------
__global__ __launch_bounds__(256) void k_attn2(const float* __restrict__ al_s, const float* __restrict__ al_d,
    const int* __restrict__ rowptr, const int* __restrict__ col,
    float* __restrict__ alpha, float* __restrict__ a0n, float* __restrict__ invden){
  int n = blockIdx.x*4 + (threadIdx.x >> 6);
  if (n >= NN) return;
  int lane = threadIdx.x & 63;
  int beg = rowptr[n], end = rowptr[n+1];
  float ald = al_d[n];
  float es = leaky(al_s[n] + ald);
  float vmax = -3.4e38f;
  for (int e = beg + lane; e < end; e += 64)
    vmax = fmaxf(vmax, leaky(al_s[col[e]] + ald));
  #pragma unroll
  for (int mk = 32; mk >= 1; mk >>= 1) vmax = fmaxf(vmax, __shfl_xor(vmax, mk, 64));
  float m = fmaxf(es, vmax);
  float sl = 0.f;
  for (int e = beg + lane; e < end; e += 64){
    float a = __expf(leaky(al_s[col[e]] + ald) - m);
    alpha[e] = a;
    sl += a;
  }
  #pragma unroll
  for (int mk = 32; mk >= 1; mk >>= 1) sl += __shfl_xor(sl, mk, 64);
  float a0 = __expf(es - m);
  float inv = 1.f/(a0 + sl + 1e-16f);
  if (lane == 0){ a0n[n] = a0*inv; invden[n] = inv; }
}

// ---------------- GAT2 gather: single pass, unrolled x4, + b2 ----------------
__global__ __launch_bounds__(128) void k_gat2g(const float* __restrict__ t2,
    const float* __restrict__ alpha, const float* __restrict__ a0n, const float* __restrict__ invden,
    const int* __restrict__ rowptr, const int* __restrict__ col,
    const float* __restrict__ b2, float* __restrict__ out){
  int n = blockIdx.x, c = threadIdx.x;
  int beg = rowptr[n], end = rowptr[n+1];
  float sum = 0.f;
  int e = beg;
  for (; e + 4 <= end; e += 4){
    int s0 = col[e], s1 = col[e+1], s2 = col[e+2], s3 = col[e+3];
    float a0_ = alpha[e],   a1_ = alpha[e+1];
    float a2_ = alpha[e+2], a3_ = alpha[e+3];
    float v0 = t2[(size_t)s0*DD + c];
    float v1 = t2[(size_t)s1*DD + c];
    float v2 = t2[(size_t)s2*DD + c];
    float v3 = t2[(size_t)s3*DD + c];
    sum = fmaf(a0_, v0, sum); sum = fmaf(a1_, v1, sum);
    sum = fmaf(a2_, v2, sum); sum = fmaf(a3_, v3, sum);
  }
  for (; e < end; ++e)
    sum = fmaf(alpha[e], t2[(size_t)col[e]*DD + c], sum);
  out[(size_t)n*DD + c] = fmaf(invden[n], sum, a0n[n]*t2[(size_t)n*DD + c]) + b2[c];
}

// ---------------- 128x128 GEMM, register-tiled, optional bias/res/relu ----------------
template<bool RELU, bool BIAS, bool RES>
__global__ __launch_bounds__(256) void k_gemm128(const float* __restrict__ X, const float* __restrict__ W,
    const float* __restrict__ bias, const float* __restrict__ res, float* __restrict__ out, int nrows){
  __shared__ __align__(16) float Xs[DD][132];   // [k][r], padded rows
  int tid = threadIdx.x;
  int n0 = blockIdx.x * 128;
  {
    int r  = tid >> 1;
    int c0 = (tid & 1) * 64;
    int n  = n0 + r;
    if (n < nrows){
      const float* xp = X + (size_t)n*DD + c0;
      #pragma unroll
      for (int i = 0; i < 16; ++i){
        float4 v = *(const float4*)(xp + i*4);
        int c = c0 + i*4;
        Xs[c][r] = v.x; Xs[c+1][r] = v.y; Xs[c+2][r] = v.z; Xs[c+3][r] = v.w;
      }
    } else {
      #pragma unroll
      for (int i = 0; i < 16; ++i){
        int c = c0 + i*4;
        Xs[c][r] = 0.f; Xs[c+1][r] = 0.f; Xs[c+2][r] = 0.f; Xs[c+3][r] = 0.f;
      }
    }
  }
  __syncthreads();
  int tc = tid & 31, tr = tid >> 5;
  int j0 = tc*4, r0 = tr*16;
  float4 acc[16];
  #pragma unroll
  for (int i = 0; i < 16; ++i) acc[i] = make_float4(0.f,0.f,0.f,0.f);
  #pragma unroll 2
  for (int k = 0; k < DD; ++k){
    float4 w4 = *(const float4*)(W + k*DD + j0);
    #pragma unroll
    for (int ii = 0; ii < 4; ++ii){
      float4 x4 = *(const float4*)&Xs[k][r0 + ii*4];
      float xs[4] = {x4.x, x4.y, x4.z, x4.w};
      #pragma unroll
      for (int jj = 0; jj < 4; ++jj){
        float xv = xs[jj];
        float4& a = acc[ii*4+jj];
        a.x = fmaf(xv, w4.x, a.x);
        a.y = fmaf(xv, w4.y, a.y);
        a.z = fmaf(xv, w4.z, a.z);
        a.w = fmaf(xv, w4.w, a.w);
      }
    }
  }
  float4 b4 = make_float4(0.f,0.f,0.f,0.f);
  if (BIAS) b4 = *(const float4*)(bias + j0);
  #pragma unroll
  for (int i = 0; i < 16; ++i){
    int n = n0 + r0 + i;
    if (n >= nrows) break;
    float4 v = acc[i];
    if (BIAS){ v.x += b4.x; v.y += b4.y; v.z += b4.z; v.w += b4.w; }
    if (RES){
      float4 rv = *(const float4*)(res + (size_t)n*DD + j0);
      v.x += rv.x; v.y += rv.y; v.z += rv.z; v.w += rv.w;
    }
    if (RELU){ v.x = fmaxf(v.x,0.f); v.y = fmaxf(v.y,0.f); v.z = fmaxf(v.z,0.f); v.w = fmaxf(v.w,0.f); }
    *(float4*)(out + (size_t)n*DD + j0) = v;
  }
}

// ---------------- graph LayerNorm (scalar mean/var over N*D) ----------------
__global__ __launch_bounds__(256) void k_ln_reduce(const float* __restrict__ x, float* __restrict__ pbuf){
  const float4* x4 = (const float4*)x;
  const int n4 = NN*DD/4;
  float s = 0.f, ss = 0.f;
  for (int i = blockIdx.x*256 + threadIdx.x; i < n4; i += gridDim.x*256){
    float4 v = x4[i];
    s  += v.x + v.y + v.z + v.w;
    ss += v.x*v.x + v.y*v.y + v.z*v.z + v.w*v.w;
  }
  #pragma unroll
  for (int m = 32; m >= 1; m >>= 1){ s += __shfl_xor(s, m, 64); ss += __shfl_xor(ss, m, 64); }
  __shared__ float sh[8];
  int wid = threadIdx.x >> 6, lane = threadIdx.x & 63;
  if (lane == 0){ sh[wid*2] = s; sh[wid*2+1] = ss; }
  __syncthreads();
  if (threadIdx.x == 0){
    float S = 0.f, SS = 0.f;
    for (int w = 0; w < 4; ++w){ S += sh[2*w]; SS += sh[2*w+1]; }
    pbuf[blockIdx.x*2] = S; pbuf[blockIdx.x*2+1] = SS;
  }
}

__global__ __launch_bounds__(256) void k_ln_stats(const float* __restrict__ pbuf, float* __restrict__ stats, int nb){
  float s = 0.f, ss = 0.f;
  for (int i = threadIdx.x; i < nb; i += 256){ s += pbuf[2*i]; ss += pbuf[2*i+1]; }
  #pragma unroll
  for (int m = 32; m >= 1; m >>= 1){ s += __shfl_xor(s, m, 64); ss += __shfl_xor(ss, m, 64); }
  __shared__ float sh[8];
  int wid = threadIdx.x >> 6, lane = threadIdx.x & 63;
  if (lane == 0){ sh[wid*2] = s; sh[wid*2+1] = ss; }
  __syncthreads();
  if (threadIdx.x == 0){
    float S = 0.f, SS = 0.f;
    for (int w = 0; w < 4; ++w){ S += sh[2*w]; SS += sh[2*w+1]; }
    const float inv = 1.f/((float)NN*(float)DD);
    float mu = S*inv;
    float var = SS*inv - mu*mu;
    stats[0] = mu;
    stats[1] = rsqrtf(var + 1e-5f);
  }
}

__global__ __launch_bounds__(256) void k_ln_apply(float* __restrict__ x, const float* __restrict__ g,
    const float* __restrict__ be, const float* __restrict__ stats){
  const int n4 = NN*DD/4;
  float mu = stats[0], rs = stats[1];
  float4* x4 = (float4*)x;
  const float4* g4p = (const float4*)g;
  const float4* b4p = (const float4*)be;
  for (int i = blockIdx.x*256 + threadIdx.x; i < n4; i += gridDim.x*256){
    int c4 = i & 31;
    float4 v = x4[i]; float4 gg = g4p[c4]; float4 bb = b4p[c4];
    v.x = (v.x - mu)*rs*gg.x + bb.x;
    v.y = (v.y - mu)*rs*gg.y + bb.y;
    v.z = (v.z - mu)*rs*gg.z + bb.z;
    v.w = (v.w - mu)*rs*gg.w + bb.w;
    x4[i] = v;
  }
}

// ---------------- final projection: val[n] = h[n].fcw + fcb ----------------
__global__ __launch_bounds__(256) void k_fdot(const float* __restrict__ h, const float* __restrict__ fw,
    const float* __restrict__ fb, float* __restrict__ val){
  int n = blockIdx.x*4 + (threadIdx.x >> 6);
  if (n >= NN) return;
  int lane = threadIdx.x & 63;
  const float* r = h + (size_t)n*DD;
  float v = r[lane]*fw[lane] + r[lane+64]*fw[lane+64];
  #pragma unroll
  for (int m = 32; m >= 1; m >>= 1) v += __shfl_xor(v, m, 64);
  if (lane == 0) val[n] = v + fb[0];
}

// ---------------- segment mean over sorted batch: one wave per graph ----------------
__global__ __launch_bounds__(64) void k_pool(const float* __restrict__ val, const int* __restrict__ batch,
                                             float* __restrict__ out){
  int g = blockIdx.x;
  int lane = threadIdx.x;
  int lo = 0, hi = NN;
  while (lo < hi){ int mid = (lo+hi)>>1; if (batch[mid] < g) lo = mid+1; else hi = mid; }
  int start = lo;
  hi = NN;
  while (lo < hi){ int mid = (lo+hi)>>1; if (batch[mid] < g+1) lo = mid+1; else hi = mid; }
  int end = lo;
  float s = 0.f;
  for (int i = start + lane; i < end; i += 64) s += val[i];
  #pragma unroll
  for (int m = 32; m >= 1; m >>= 1) s += __shfl_xor(s, m, 64);
  if (lane == 0) out[g] = s / fmaxf((float)(end - start), 1.f);
}

extern "C" void kernel_launch(void* const* d_in, const int* in_sizes, int n_in,
                              void* d_out, int out_size, void* d_ws, size_t ws_size,
                              hipStream_t stream){
  const float* x   = (const float*)d_in[0];
  const int*   ei  = (const int*)d_in[1];
  const int* batch = (const int*)d_in[2];
  const float* W1  = (const float*)d_in[3];
  const float* as1 = (const float*)d_in[4];
  const float* ad1 = (const float*)d_in[5];
  const float* b1  = (const float*)d_in[6];
  const float* W2  = (const float*)d_in[7];
  const float* as2 = (const float*)d_in[8];
  const float* ad2 = (const float*)d_in[9];
  const float* b2  = (const float*)d_in[10];
  const float* fc1w= (const float*)d_in[11];
  const float* fc1b= (const float*)d_in[12];
  const float* fc2w= (const float*)d_in[13];
  const float* fc2b= (const float*)d_in[14];
  const float* fc3w= (const float*)d_in[15];
  const float* fc3b= (const float*)d_in[16];
  const float* fc4w= (const float*)d_in[17];
  const float* fc4b= (const float*)d_in[18];
  const float* g1  = (const float*)d_in[19];
  const float* be1 = (const float*)d_in[20];
  const float* g2  = (const float*)d_in[21];
  const float* be2 = (const float*)d_in[22];
  const float* fcw = (const float*)d_in[23];
  const float* fcb = (const float*)d_in[24];
  float* out = (float*)d_out;
  (void)in_sizes; (void)n_in; (void)out_size; (void)ws_size;

  char* ws = (char*)d_ws;
  size_t off = 0;
  auto alloc = [&](size_t bytes)->void*{
    void* p = ws + off;
    off += (bytes + 255) & ~(size_t)255;
    return p;
  };
  float* A    = (float*)alloc((size_t)NN*DD*4);
  float* B    = (float*)alloc((size_t)NN*DD*4);
  float* C    = (float*)alloc((size_t)NN*DD*4);   // doubles as alpha1 [E,8] during layer-1 GAT
  float* als1 = (float*)alloc((size_t)NN*NH*4);
  float* ald1 = (float*)alloc((size_t)NN*NH*4);
  float* a0n1 = (float*)alloc((size_t)NN*NH*4);
  float* inv1 = (float*)alloc((size_t)NN*NH*4);
  float* als2 = (float*)alloc((size_t)NN*4);
  float* ald2 = (float*)alloc((size_t)NN*4);
  float* a0n2 = (float*)alloc((size_t)NN*4);
  float* inv2 = (float*)alloc((size_t)NN*4);
  float* alpha2 = (float*)alloc((size_t)NE*4);
  int*   cnt    = (int*)alloc((size_t)NN*4);
  int*   rowptr = (int*)alloc((size_t)(NN+1)*4);
  int*   wo     = (int*)alloc((size_t)NN*4);
  int*   col    = (int*)alloc((size_t)NE*4);
  int*   ipart  = (int*)alloc(256*4);
  float* pbuf   = (float*)alloc(1024*2*4);
  float* stats  = (float*)alloc(2*4);
  float* val    = (float*)alloc((size_t)NN*4);

  float* alpha1 = C;   // alias: C is dead until fc2 output

  const int* esrc = ei;
  const int* edst = ei + NE;

  hipMemsetAsync(cnt, 0, (size_t)NN*4, stream);

  // CSR by dst (self-loops handled analytically in aggregation)
  k_count<<<(NE+255)/256, 256, 0, stream>>>(edst, cnt);
  const int NB1 = (NN + 511)/512;
  k_scan1<<<NB1, 512, 0, stream>>>(cnt, rowptr, ipart);
  k_scan2<<<1, 256, 0, stream>>>(ipart, NB1);
  k_scan3<<<NB1, 512, 0, stream>>>(rowptr, wo, ipart, cnt);
  k_fill<<<(NE+255)/256, 256, 0, stream>>>(esrc, edst, wo, col);

  const int WB = (NN + 3)/4;   // wave-per-node kernels, 4 waves/block

  // GAT layer 1
  k_lin1<<<NN, 128, 0, stream>>>(x, W1, as1, ad1, A, als1, ald1);
  k_attn1<<<WB, 256, 0, stream>>>(als1, ald1, rowptr, col, alpha1, a0n1, inv1);
  k_gat1g<<<NN, 128, 0, stream>>>(A, alpha1, a0n1, inv1, rowptr, col, b1, B);

  const int GB = (NN + 127)/128;
  // fc1 (relu), fc2 (+res h1, relu)
  k_gemm128<true,  true, false><<<GB, 256, 0, stream>>>(B, fc1w, fc1b, nullptr, A, NN);
  k_gemm128<true,  true, true ><<<GB, 256, 0, stream>>>(A, fc2w, fc2b, B,       C, NN);

  // LN1 (graph mode)
  k_ln_reduce<<<1024, 256, 0, stream>>>(C, pbuf);
  k_ln_stats<<<1, 256, 0, stream>>>(pbuf, stats, 1024);
  k_ln_apply<<<1024, 256, 0, stream>>>(C, g1, be1, stats);

  // GAT layer 2 (t2 = C @ W2)
  k_gemm128<false, false, false><<<GB, 256, 0, stream>>>(C, W2, nullptr, nullptr, A, NN);
  k_al2<<<WB, 256, 0, stream>>>(A, as2, ad2, als2, ald2);
  k_attn2<<<WB, 256, 0, stream>>>(als2, ald2, rowptr, col, alpha2, a0n2, inv2);
  k_gat2g<<<NN, 128, 0, stream>>>(A, alpha2, a0n2, inv2, rowptr, col, b2, B);

  // fc3 (relu), fc4 (+res C, no relu)
  k_gemm128<true,  true, false><<<GB, 256, 0, stream>>>(B, fc3w, fc3b, nullptr, A, NN);
  k_gemm128<false, true, true ><<<GB, 256, 0, stream>>>(A, fc4w, fc4b, C,       B, NN);

  // LN2
  k_ln_reduce<<<1024, 256, 0, stream>>>(B, pbuf);
  k_ln_stats<<<1, 256, 0, stream>>>(pbuf, stats, 1024);
  k_ln_apply<<<1024, 256, 0, stream>>>(B, g2, be2, stats);

  // final projection + global mean pool per graph (no atomics)
  k_fdot<<<WB, 256, 0, stream>>>(B, fcw, fcb, val);
  k_pool<<<NG, 64, 0, stream>>>(val, batch, out);
}

// Round 4
// 911.102 us; speedup vs baseline: 1.4685x; 1.1002x over previous
//
#include <hip/hip_runtime.h>
#include <cstdint>

#define NN 100000
#define NE 1600000
#define DI 9
#define DD 128
#define NH 8
#define NG 1000

typedef unsigned int uint;

__device__ __forceinline__ float leaky(float x){ return x > 0.f ? x : 0.2f*x; }
__device__ __forceinline__ uint f2bf(float f){            // round-to-nearest-even bf16 (finite inputs)
  uint u = __float_as_uint(f);
  return (u + 0x7fffu + ((u>>16)&1u)) >> 16;
}
__device__ __forceinline__ float bflo(uint p){ return __uint_as_float(p << 16); }
__device__ __forceinline__ float bfhi(uint p){ return __uint_as_float(p & 0xffff0000u); }

// ---------------- CSR build ----------------
__global__ void k_count(const int* __restrict__ dst, int* __restrict__ cnt){
  int i = blockIdx.x*blockDim.x + threadIdx.x;
  if (i < NE) atomicAdd(&cnt[dst[i]], 1);
}

__global__ __launch_bounds__(512) void k_scan1(const int* __restrict__ cnt, int* __restrict__ rowptr,
                                               int* __restrict__ partial){
  __shared__ int sh[512];
  int tid = threadIdx.x;
  int i = blockIdx.x*512 + tid;
  int v = (i < NN) ? cnt[i] : 0;
  sh[tid] = v;
  __syncthreads();
  for (int off = 1; off < 512; off <<= 1){
    int t = (tid >= off) ? sh[tid-off] : 0;
    __syncthreads();
    sh[tid] += t;
    __syncthreads();
  }
  if (i < NN) rowptr[i] = sh[tid] - v;          // exclusive
  if (tid == 511) partial[blockIdx.x] = sh[511]; // block total
}

__global__ __launch_bounds__(256) void k_scan2(int* partial, int nb){
  __shared__ int sh[256];
  int tid = threadIdx.x;
  int v = (tid < nb) ? partial[tid] : 0;
  sh[tid] = v;
  __syncthreads();
  for (int off = 1; off < 256; off <<= 1){
    int t = (tid >= off) ? sh[tid-off] : 0;
    __syncthreads();
    sh[tid] += t;
    __syncthreads();
  }
  if (tid < nb) partial[tid] = sh[tid] - v;      // exclusive
}

__global__ __launch_bounds__(512) void k_scan3(int* __restrict__ rowptr, int* __restrict__ wo,
                                               const int* __restrict__ partial, const int* __restrict__ cnt){
  int i = blockIdx.x*512 + threadIdx.x;
  if (i < NN){
    int v = rowptr[i] + partial[blockIdx.x];
    rowptr[i] = v;
    wo[i] = v;
    if (i == NN-1) rowptr[NN] = v + cnt[i];
  }
}

__global__ void k_fill(const int* __restrict__ src, const int* __restrict__ dst,
                       int* __restrict__ wo, int* __restrict__ col){
  int i = blockIdx.x*blockDim.x + threadIdx.x;
  if (i < NE){
    int p = atomicAdd(&wo[dst[i]], 1);
    col[p] = src[i];
  }
}

// ---------------- GAT1 linear (x@W1) + logits; writes bf16-packed feature table ----------------
__global__ __launch_bounds__(128) void k_lin1(const float* __restrict__ x, const float* __restrict__ W1,
    const float* __restrict__ as1, const float* __restrict__ ad1,
    uint* __restrict__ t1b, float* __restrict__ al_s, float* __restrict__ al_d){
  int n = blockIdx.x;
  int c = threadIdx.x;
  const float* xr = x + n*DI;
  float t = 0.f;
  #pragma unroll
  for (int k = 0; k < DI; ++k) t = fmaf(xr[k], W1[k*DD+c], t);
  uint mybf = f2bf(t);
  uint pbf  = (uint)__shfl_xor((int)mybf, 1, 64);
  if (!(c & 1)) t1b[(size_t)n*64 + (c>>1)] = mybf | (pbf<<16);
  float vs = t * as1[c];
  float vd = t * ad1[c];
  #pragma unroll
  for (int m = 8; m >= 1; m >>= 1){ vs += __shfl_xor(vs, m, 16); vd += __shfl_xor(vd, m, 16); }
  if ((c & 15) == 0){
    al_s[n*NH + (c>>4)] = vs;
    al_d[n*NH + (c>>4)] = vd;
  }
}

// ---------------- attn coeffs layer 1: wave per node, 8 edges x 8 heads per chunk ----------------
__global__ __launch_bounds__(256) void k_attn1(const float* __restrict__ al_s, const float* __restrict__ al_d,
    const int* __restrict__ rowptr, const int* __restrict__ col,
    float* __restrict__ alpha, float* __restrict__ a0n, float* __restrict__ invden){
  int n = blockIdx.x*4 + (threadIdx.x >> 6);
  if (n >= NN) return;
  int lane = threadIdx.x & 63;
  int h = lane & 7, j = lane >> 3;
  int beg = rowptr[n], end = rowptr[n+1];
  float ald = al_d[n*NH + h];
  float es = leaky(al_s[n*NH + h] + ald);       // self-loop
  float vmax = -3.4e38f;
  for (int e = beg + j; e < end; e += 8){
    int s = col[e];
    vmax = fmaxf(vmax, leaky(al_s[s*NH + h] + ald));
  }
  vmax = fmaxf(vmax, __shfl_xor(vmax, 8, 64));
  vmax = fmaxf(vmax, __shfl_xor(vmax, 16, 64));
  vmax = fmaxf(vmax, __shfl_xor(vmax, 32, 64));
  float m = fmaxf(es, vmax);
  float sl = 0.f;
  for (int e = beg + j; e < end; e += 8){
    int s = col[e];
    float a = __expf(leaky(al_s[s*NH + h] + ald) - m);
    alpha[(size_t)e*NH + h] = a;
    sl += a;
  }
  sl += __shfl_xor(sl, 8, 64);
  sl += __shfl_xor(sl, 16, 64);
  sl += __shfl_xor(sl, 32, 64);
  float a0 = __expf(es - m);
  float inv = 1.f/(a0 + sl + 1e-16f);
  if (j == 0){
    a0n[n*NH + h]    = a0*inv;
    invden[n*NH + h] = inv;
  }
}

// ---------------- GAT1 gather: wave per node, bf16 rows, 2ch/lane, + b1, ReLU ----------------
__global__ __launch_bounds__(256) void k_gat1g(const uint* __restrict__ t1b,
    const float* __restrict__ alpha, const float* __restrict__ a0n, const float* __restrict__ invden,
    const int* __restrict__ rowptr, const int* __restrict__ col,
    const float* __restrict__ b1, float* __restrict__ out){
  int n = blockIdx.x*4 + (threadIdx.x >> 6);
  if (n >= NN) return;
  int lane = threadIdx.x & 63;
  int h = lane >> 3;                  // head of channels (2*lane, 2*lane+1)
  int beg = rowptr[n], end = rowptr[n+1];
  float s0 = 0.f, s1 = 0.f;
  int e = beg;
  for (; e + 4 <= end; e += 4){
    int c0 = col[e], c1 = col[e+1], c2 = col[e+2], c3 = col[e+3];
    float a0_ = alpha[(size_t)e*NH + h];
    float a1_ = alpha[(size_t)(e+1)*NH + h];
    float a2_ = alpha[(size_t)(e+2)*NH + h];
    float a3_ = alpha[(size_t)(e+3)*NH + h];
    uint p0 = t1b[(size_t)c0*64 + lane];
    uint p1 = t1b[(size_t)c1*64 + lane];
    uint p2 = t1b[(size_t)c2*64 + lane];
    uint p3 = t1b[(size_t)c3*64 + lane];
    s0 = fmaf(a0_, bflo(p0), s0); s1 = fmaf(a0_, bfhi(p0), s1);
    s0 = fmaf(a1_, bflo(p1), s0); s1 = fmaf(a1_, bfhi(p1), s1);
    s0 = fmaf(a2_, bflo(p2), s0); s1 = fmaf(a2_, bfhi(p2), s1);
    s0 = fmaf(a3_, bflo(p3), s0); s1 = fmaf(a3_, bfhi(p3), s1);
  }
  for (; e < end; ++e){
    float a = alpha[(size_t)e*NH + h];
    uint p = t1b[(size_t)col[e]*64 + lane];
    s0 = fmaf(a, bflo(p), s0); s1 = fmaf(a, bfhi(p), s1);
  }
  uint ps = t1b[(size_t)n*64 + lane];
  float inv = invden[n*NH + h], az = a0n[n*NH + h];
  float2 bb = ((const float2*)b1)[lane];
  float r0 = fmaf(inv, s0, az*bflo(ps)) + bb.x;
  float r1 = fmaf(inv, s1, az*bfhi(ps)) + bb.y;
  ((float2*)out)[(size_t)n*64 + lane] = make_float2(fmaxf(r0,0.f), fmaxf(r1,0.f));
}

// ---------------- GAT2 attention logits from bf16 table ----------------
__global__ __launch_bounds__(256) void k_al2(const uint* __restrict__ t2b,
    const float* __restrict__ as2, const float* __restrict__ ad2,
    float* __restrict__ al_s, float* __restrict__ al_d){
  int n = blockIdx.x*4 + (threadIdx.x >> 6);
  if (n >= NN) return;
  int lane = threadIdx.x & 63;
  uint p = t2b[(size_t)n*64 + lane];
  float v0 = bflo(p), v1 = bfhi(p);
  float2 s2 = ((const float2*)as2)[lane];
  float2 d2 = ((const float2*)ad2)[lane];
  float vs = v0*s2.x + v1*s2.y;
  float vd = v0*d2.x + v1*d2.y;
  #pragma unroll
  for (int m = 32; m >= 1; m >>= 1){ vs += __shfl_xor(vs, m, 64); vd += __shfl_xor(vd, m, 64); }
  if (lane == 0){ al_s[n] = vs; al_d[n] = vd; }
}

// ---------------- attn coeffs layer 2: wave per node ----------------
__global__ __launch_bounds__(256) void k_attn2(const float* __restrict__ al_s, const float* __restrict__ al_d,
    const int* __restrict__ rowptr, const int* __restrict__ col,
    float* __restrict__ alpha, float* __restrict__ a0n, float* __restrict__ invden){
  int n = blockIdx.x*4 + (threadIdx.x >> 6);
  if (n >= NN) return;
  int lane = threadIdx.x & 63;
  int beg = rowptr[n], end = rowptr[n+1];
  float ald = al_d[n];
  float es = leaky(al_s[n] + ald);
  float vmax = -3.4e38f;
  for (int e = beg + lane; e < end; e += 64)
    vmax = fmaxf(vmax, leaky(al_s[col[e]] + ald));
  #pragma unroll
  for (int mk = 32; mk >= 1; mk >>= 1) vmax = fmaxf(vmax, __shfl_xor(vmax, mk, 64));
  float m = fmaxf(es, vmax);
  float sl = 0.f;
  for (int e = beg + lane; e < end; e += 64){
    float a = __expf(leaky(al_s[col[e]] + ald) - m);
    alpha[e] = a;
    sl += a;
  }
  #pragma unroll
  for (int mk = 32; mk >= 1; mk >>= 1) sl += __shfl_xor(sl, mk, 64);
  float a0 = __expf(es - m);
  float inv = 1.f/(a0 + sl + 1e-16f);
  if (lane == 0){ a0n[n] = a0*inv; invden[n] = inv; }
}

// ---------------- GAT2 gather: wave per node, bf16 rows, + b2 ----------------
__global__ __launch_bounds__(256) void k_gat2g(const uint* __restrict__ t2b,
    const float* __restrict__ alpha, const float* __restrict__ a0n, const float* __restrict__ invden,
    const int* __restrict__ rowptr, const int* __restrict__ col,
    const float* __restrict__ b2, float* __restrict__ out){
  int n = blockIdx.x*4 + (threadIdx.x >> 6);
  if (n >= NN) return;
  int lane = threadIdx.x & 63;
  int beg = rowptr[n], end = rowptr[n+1];
  float s0 = 0.f, s1 = 0.f;
  int e = beg;
  for (; e + 4 <= end; e += 4){
    int c0 = col[e], c1 = col[e+1], c2 = col[e+2], c3 = col[e+3];
    float a0_ = alpha[e],   a1_ = alpha[e+1];
    float a2_ = alpha[e+2], a3_ = alpha[e+3];
    uint p0 = t2b[(size_t)c0*64 + lane];
    uint p1 = t2b[(size_t)c1*64 + lane];
    uint p2 = t2b[(size_t)c2*64 + lane];
    uint p3 = t2b[(size_t)c3*64 + lane];
    s0 = fmaf(a0_, bflo(p0), s0); s1 = fmaf(a0_, bfhi(p0), s1);
    s0 = fmaf(a1_, bflo(p1), s0); s1 = fmaf(a1_, bfhi(p1), s1);
    s0 = fmaf(a2_, bflo(p2), s0); s1 = fmaf(a2_, bfhi(p2), s1);
    s0 = fmaf(a3_, bflo(p3), s0); s1 = fmaf(a3_, bfhi(p3), s1);
  }
  for (; e < end; ++e){
    float a = alpha[e];
    uint p = t2b[(size_t)col[e]*64 + lane];
    s0 = fmaf(a, bflo(p), s0); s1 = fmaf(a, bfhi(p), s1);
  }
  uint ps = t2b[(size_t)n*64 + lane];
  float inv = invden[n], az = a0n[n];
  float2 bb = ((const float2*)b2)[lane];
  float r0 = fmaf(inv, s0, az*bflo(ps)) + bb.x;
  float r1 = fmaf(inv, s1, az*bfhi(ps)) + bb.y;
  ((float2*)out)[(size_t)n*64 + lane] = make_float2(r0, r1);
}

// ---------------- 128x128 GEMM, register-tiled; fp32 and/or packed-bf16 output ----------------
template<bool RELU, bool BIAS, bool RES, bool F32OUT, bool BF16OUT>
__global__ __launch_bounds__(256) void k_gemm128(const float* __restrict__ X, const float* __restrict__ W,
    const float* __restrict__ bias, const float* __restrict__ res, float* __restrict__ out,
    uint* __restrict__ outb, int nrows){
  __shared__ __align__(16) float Xs[DD][132];   // [k][r], padded rows
  int tid = threadIdx.x;
  int n0 = blockIdx.x * 128;
  {
    int r  = tid >> 1;
    int c0 = (tid & 1) * 64;
    int n  = n0 + r;
    if (n < nrows){
      const float* xp = X + (size_t)n*DD + c0;
      #pragma unroll
      for (int i = 0; i < 16; ++i){
        float4 v = *(const float4*)(xp + i*4);
        int c = c0 + i*4;
        Xs[c][r] = v.x; Xs[c+1][r] = v.y; Xs[c+2][r] = v.z; Xs[c+3][r] = v.w;
      }
    } else {
      #pragma unroll
      for (int i = 0; i < 16; ++i){
        int c = c0 + i*4;
        Xs[c][r] = 0.f; Xs[c+1][r] = 0.f; Xs[c+2][r] = 0.f; Xs[c+3][r] = 0.f;
      }
    }
  }
  __syncthreads();
  int tc = tid & 31, tr = tid >> 5;
  int j0 = tc*4, r0 = tr*16;
  float4 acc[16];
  #pragma unroll
  for (int i = 0; i < 16; ++i) acc[i] = make_float4(0.f,0.f,0.f,0.f);
  #pragma unroll 2
  for (int k = 0; k < DD; ++k){
    float4 w4 = *(const float4*)(W + k*DD + j0);
    #pragma unroll
    for (int ii = 0; ii < 4; ++ii){
      float4 x4 = *(const float4*)&Xs[k][r0 + ii*4];
      float xs[4] = {x4.x, x4.y, x4.z, x4.w};
      #pragma unroll
      for (int jj = 0; jj < 4; ++jj){
        float xv = xs[jj];
        float4& a = acc[ii*4+jj];
        a.x = fmaf(xv, w4.x, a.x);
        a.y = fmaf(xv, w4.y, a.y);
        a.z = fmaf(xv, w4.z, a.z);
        a.w = fmaf(xv, w4.w, a.w);
      }
    }
  }
  float4 b4 = make_float4(0.f,0.f,0.f,0.f);
  if (BIAS) b4 = *(const float4*)(bias + j0);
  #pragma unroll
  for (int i = 0; i < 16; ++i){
    int n = n0 + r0 + i;
    if (n >= nrows) break;
    float4 v = acc[i];
    if (BIAS){ v.x += b4.x; v.y += b4.y; v.z += b4.z; v.w += b4.w; }
    if (RES){
      float4 rv = *(const float4*)(res + (size_t)n*DD + j0);
      v.x += rv.x; v.y += rv.y; v.z += rv.z; v.w += rv.w;
    }
    if (RELU){ v.x = fmaxf(v.x,0.f); v.y = fmaxf(v.y,0.f); v.z = fmaxf(v.z,0.f); v.w = fmaxf(v.w,0.f); }
    if (F32OUT) *(float4*)(out + (size_t)n*DD + j0) = v;
    if (BF16OUT){
      uint2 pk;
      pk.x = f2bf(v.x) | (f2bf(v.y)<<16);
      pk.y = f2bf(v.z) | (f2bf(v.w)<<16);
      *(uint2*)(outb + (size_t)n*64 + (j0>>1)) = pk;
    }
  }
}

// ---------------- graph LayerNorm (scalar mean/var over N*D) ----------------
__global__ __launch_bounds__(256) void k_ln_reduce(const float* __restrict__ x, float* __restrict__ pbuf){
  const float4* x4 = (const float4*)x;
  const int n4 = NN*DD/4;
  float s = 0.f, ss = 0.f;
  for (int i = blockIdx.x*256 + threadIdx.x; i < n4; i += gridDim.x*256){
    float4 v = x4[i];
    s  += v.x + v.y + v.z + v.w;
    ss += v.x*v.x + v.y*v.y + v.z*v.z + v.w*v.w;
  }
  #pragma unroll
  for (int m = 32; m >= 1; m >>= 1){ s += __shfl_xor(s, m, 64); ss += __shfl_xor(ss, m, 64); }
  __shared__ float sh[8];
  int wid = threadIdx.x >> 6, lane = threadIdx.x & 63;
  if (lane == 0){ sh[wid*2] = s; sh[wid*2+1] = ss; }
  __syncthreads();
  if (threadIdx.x == 0){
    float S = 0.f, SS = 0.f;
    for (int w = 0; w < 4; ++w){ S += sh[2*w]; SS += sh[2*w+1]; }
    pbuf[blockIdx.x*2] = S; pbuf[blockIdx.x*2+1] = SS;
  }
}

__global__ __launch_bounds__(256) void k_ln_stats(const float* __restrict__ pbuf, float* __restrict__ stats, int nb){
  float s = 0.f, ss = 0.f;
  for (int i = threadIdx.x; i < nb; i += 256){ s += pbuf[2*i]; ss += pbuf[2*i+1]; }
  #pragma unroll
  for (int m = 32; m >= 1; m >>= 1){ s += __shfl_xor(s, m, 64); ss += __shfl_xor(ss, m, 64); }
  __shared__ float sh[8];
  int wid = threadIdx.x >> 6, lane = threadIdx.x & 63;
  if (lane == 0){ sh[wid*2] = s; sh[wid*2+1] = ss; }
  __syncthreads();
  if (threadIdx.x == 0){
    float S = 0.f, SS = 0.f;
    for (int w = 0; w < 4; ++w){ S += sh[2*w]; SS += sh[2*w+1]; }
    const float inv = 1.f/((float)NN*(float)DD);
    float mu = S*inv;
    float var = SS*inv - mu*mu;
    stats[0] = mu;
    stats[1] = rsqrtf(var + 1e-5f);
  }
}

__global__ __launch_bounds__(256) void k_ln_apply(float* __restrict__ x, const float* __restrict__ g,
    const float* __restrict__ be, const float* __restrict__ stats){
  const int n4 = NN*DD/4;
  float mu = stats[0], rs = stats[1];
  float4* x4 = (float4*)x;
  const float4* g4p = (const float4*)g;
  const float4* b4p = (const float4*)be;
  for (int i = blockIdx.x*256 + threadIdx.x; i < n4; i += gridDim.x*256){
    int c4 = i & 31;
    float4 v = x4[i]; float4 gg = g4p[c4]; float4 bb = b4p[c4];
    v.x = (v.x - mu)*rs*gg.x + bb.x;
    v.y = (v.y - mu)*rs*gg.y + bb.y;
    v.z = (v.z - mu)*rs*gg.z + bb.z;
    v.w = (v.w - mu)*rs*gg.w + bb.w;
    x4[i] = v;
  }
}

// ---------------- final projection: val[n] = h[n].fcw + fcb ----------------
__global__ __launch_bounds__(256) void k_fdot(const float* __restrict__ h, const float* __restrict__ fw,
    const float* __restrict__ fb, float* __restrict__ val){
  int n = blockIdx.x*4 + (threadIdx.x >> 6);
  if (n >= NN) return;
  int lane = threadIdx.x & 63;
  const float* r = h + (size_t)n*DD;
  float v = r[lane]*fw[lane] + r[lane+64]*fw[lane+64];
  #pragma unroll
  for (int m = 32; m >= 1; m >>= 1) v += __shfl_xor(v, m, 64);
  if (lane == 0) val[n] = v + fb[0];
}

// ---------------- segment mean over sorted batch: one wave per graph ----------------
__global__ __launch_bounds__(64) void k_pool(const float* __restrict__ val, const int* __restrict__ batch,
                                             float* __restrict__ out){
  int g = blockIdx.x;
  int lane = threadIdx.x;
  int lo = 0, hi = NN;
  while (lo < hi){ int mid = (lo+hi)>>1; if (batch[mid] < g) lo = mid+1; else hi = mid; }
  int start = lo;
  hi = NN;
  while (lo < hi){ int mid = (lo+hi)>>1; if (batch[mid] < g+1) lo = mid+1; else hi = mid; }
  int end = lo;
  float s = 0.f;
  for (int i = start + lane; i < end; i += 64) s += val[i];
  #pragma unroll
  for (int m = 32; m >= 1; m >>= 1) s += __shfl_xor(s, m, 64);
  if (lane == 0) out[g] = s / fmaxf((float)(end - start), 1.f);
}

extern "C" void kernel_launch(void* const* d_in, const int* in_sizes, int n_in,
                              void* d_out, int out_size, void* d_ws, size_t ws_size,
                              hipStream_t stream){
  const float* x   = (const float*)d_in[0];
  const int*   ei  = (const int*)d_in[1];
  const int* batch = (const int*)d_in[2];
  const float* W1  = (const float*)d_in[3];
  const float* as1 = (const float*)d_in[4];
  const float* ad1 = (const float*)d_in[5];
  const float* b1  = (const float*)d_in[6];
  const float* W2  = (const float*)d_in[7];
  const float* as2 = (const float*)d_in[8];
  const float* ad2 = (const float*)d_in[9];
  const float* b2  = (const float*)d_in[10];
  const float* fc1w= (const float*)d_in[11];
  const float* fc1b= (const float*)d_in[12];
  const float* fc2w= (const float*)d_in[13];
  const float* fc2b= (const float*)d_in[14];
  const float* fc3w= (const float*)d_in[15];
  const float* fc3b= (const float*)d_in[16];
  const float* fc4w= (const float*)d_in[17];
  const float* fc4b= (const float*)d_in[18];
  const float* g1  = (const float*)d_in[19];
  const float* be1 = (const float*)d_in[20];
  const float* g2  = (const float*)d_in[21];
  const float* be2 = (const float*)d_in[22];
  const float* fcw = (const float*)d_in[23];
  const float* fcb = (const float*)d_in[24];
  float* out = (float*)d_out;
  (void)in_sizes; (void)n_in; (void)out_size; (void)ws_size;

  char* ws = (char*)d_ws;
  size_t off = 0;
  auto alloc = [&](size_t bytes)->void*{
    void* p = ws + off;
    off += (bytes + 255) & ~(size_t)255;
    return p;
  };
  float* A    = (float*)alloc((size_t)NN*DD*4);   // first half doubles as bf16 tables t1b/t2b
  float* B    = (float*)alloc((size_t)NN*DD*4);
  float* C    = (float*)alloc((size_t)NN*DD*4);   // doubles as alpha1 [E,8] during layer-1 GAT
  float* als1 = (float*)alloc((size_t)NN*NH*4);
  float* ald1 = (float*)alloc((size_t)NN*NH*4);
  float* a0n1 = (float*)alloc((size_t)NN*NH*4);
  float* inv1 = (float*)alloc((size_t)NN*NH*4);
  float* als2 = (float*)alloc((size_t)NN*4);
  float* ald2 = (float*)alloc((size_t)NN*4);
  float* a0n2 = (float*)alloc((size_t)NN*4);
  float* inv2 = (float*)alloc((size_t)NN*4);
  float* alpha2 = (float*)alloc((size_t)NE*4);
  int*   cnt    = (int*)alloc((size_t)NN*4);
  int*   rowptr = (int*)alloc((size_t)(NN+1)*4);
  int*   wo     = (int*)alloc((size_t)NN*4);
  int*   col    = (int*)alloc((size_t)NE*4);
  int*   ipart  = (int*)alloc(256*4);
  float* pbuf   = (float*)alloc(1024*2*4);
  float* stats  = (float*)alloc(2*4);
  float* val    = (float*)alloc((size_t)NN*4);

  float* alpha1 = C;     // alias: C is dead until fc2 output
  uint*  t1b    = (uint*)A;   // alias: A is dead until fc1 output
  uint*  t2b    = (uint*)A;   // alias: A is dead again after fc2 consumes it

  const int* esrc = ei;
  const int* edst = ei + NE;

  hipMemsetAsync(cnt, 0, (size_t)NN*4, stream);

  // CSR by dst (self-loops handled analytically in aggregation)
  k_count<<<(NE+255)/256, 256, 0, stream>>>(edst, cnt);
  const int NB1 = (NN + 511)/512;
  k_scan1<<<NB1, 512, 0, stream>>>(cnt, rowptr, ipart);
  k_scan2<<<1, 256, 0, stream>>>(ipart, NB1);
  k_scan3<<<NB1, 512, 0, stream>>>(rowptr, wo, ipart, cnt);
  k_fill<<<(NE+255)/256, 256, 0, stream>>>(esrc, edst, wo, col);

  const int WB = (NN + 3)/4;   // wave-per-node kernels, 4 waves/block

  // GAT layer 1 (bf16 feature table)
  k_lin1<<<NN, 128, 0, stream>>>(x, W1, as1, ad1, t1b, als1, ald1);
  k_attn1<<<WB, 256, 0, stream>>>(als1, ald1, rowptr, col, alpha1, a0n1, inv1);
  k_gat1g<<<WB, 256, 0, stream>>>(t1b, alpha1, a0n1, inv1, rowptr, col, b1, B);

  const int GB = (NN + 127)/128;
  // fc1 (relu), fc2 (+res h1, relu)
  k_gemm128<true,  true, false, true, false><<<GB, 256, 0, stream>>>(B, fc1w, fc1b, nullptr, A, nullptr, NN);
  k_gemm128<true,  true, true,  true, false><<<GB, 256, 0, stream>>>(A, fc2w, fc2b, B,       C, nullptr, NN);

  // LN1 (graph mode)
  k_ln_reduce<<<1024, 256, 0, stream>>>(C, pbuf);
  k_ln_stats<<<1, 256, 0, stream>>>(pbuf, stats, 1024);
  k_ln_apply<<<1024, 256, 0, stream>>>(C, g1, be1, stats);

  // GAT layer 2: t2b = bf16(C @ W2)
  k_gemm128<false, false, false, false, true><<<GB, 256, 0, stream>>>(C, W2, nullptr, nullptr, nullptr, t2b, NN);
  k_al2<<<WB, 256, 0, stream>>>(t2b, as2, ad2, als2, ald2);
  k_attn2<<<WB, 256, 0, stream>>>(als2, ald2, rowptr, col, alpha2, a0n2, inv2);
  k_gat2g<<<WB, 256, 0, stream>>>(t2b, alpha2, a0n2, inv2, rowptr, col, b2, B);

  // fc3 (relu), fc4 (+res C, no relu)
  k_gemm128<true,  true, false, true, false><<<GB, 256, 0, stream>>>(B, fc3w, fc3b, nullptr, A, nullptr, NN);
  k_gemm128<false, true, true,  true, false><<<GB, 256, 0, stream>>>(A, fc4w, fc4b, C,       B, nullptr, NN);

  // LN2
  k_ln_reduce<<<1024, 256, 0, stream>>>(B, pbuf);
  k_ln_stats<<<1, 256, 0, stream>>>(pbuf, stats, 1024);
  k_ln_apply<<<1024, 256, 0, stream>>>(B, g2, be2, stats);

  // final projection + global mean pool per graph (no atomics)
  k_fdot<<<WB, 256, 0, stream>>>(B, fcw, fcb, val);
  k_pool<<<NG, 64, 0, stream>>>(val, batch, out);
}

// Round 5
// 762.571 us; speedup vs baseline: 1.7546x; 1.1948x over previous
//
#include <hip/hip_runtime.h>
#include <cstdint>

#define NN 100000
#define NE 1600000
#define DI 9
#define DD 128
#define NH 8
#define NG 1000

#define NBK 3125            // buckets = dst>>5; 3125*32 == 100000 exactly
#define NBLK 256            // partition blocks
#define EPB (NE/NBLK)       // 6250 edges per block (exact)

typedef unsigned int uint;

__device__ __forceinline__ float leaky(float x){ return x > 0.f ? x : 0.2f*x; }
__device__ __forceinline__ uint f2bf(float f){            // round-to-nearest-even bf16 (finite inputs)
  uint u = __float_as_uint(f);
  return (u + 0x7fffu + ((u>>16)&1u)) >> 16;
}
__device__ __forceinline__ float bflo(uint p){ return __uint_as_float(p << 16); }
__device__ __forceinline__ float bfhi(uint p){ return __uint_as_float(p & 0xffff0000u); }

// ================= CSR build: atomic-free bucket partition =================
// P1: per-block bucket histogram
__global__ __launch_bounds__(512) void k_hist(const int* __restrict__ dst, int* __restrict__ hist){
  __shared__ int h[NBK];
  for (int i = threadIdx.x; i < NBK; i += 512) h[i] = 0;
  __syncthreads();
  int blk = blockIdx.x;
  int beg = blk*EPB, end = beg + EPB;
  for (int i = beg + threadIdx.x; i < end; i += 512)
    atomicAdd(&h[dst[i] >> 5], 1);
  __syncthreads();
  for (int b = threadIdx.x; b < NBK; b += 512) hist[(size_t)blk*NBK + b] = h[b];
}

// P2a: for each bucket, exclusive prefix across blocks (in place) + bucket total
__global__ __launch_bounds__(256) void k_bsum(int* __restrict__ hist, int* __restrict__ bsum){
  int b = blockIdx.x*256 + threadIdx.x;
  if (b >= NBK) return;
  int run = 0;
  for (int k = 0; k < NBLK; ++k){
    int t = hist[(size_t)k*NBK + b];
    hist[(size_t)k*NBK + b] = run;
    run += t;
  }
  bsum[b] = run;
}

// P2b: exclusive scan over bucket totals -> bucket base offsets
__global__ __launch_bounds__(1024) void k_bscan(const int* __restrict__ bsum, int* __restrict__ bbase){
  __shared__ int sh[1024];
  __shared__ int carry;
  if (threadIdx.x == 0) carry = 0;
  __syncthreads();
  for (int c0 = 0; c0 < NBK; c0 += 1024){
    int i = c0 + threadIdx.x;
    int v = (i < NBK) ? bsum[i] : 0;
    sh[threadIdx.x] = v;
    __syncthreads();
    for (int off = 1; off < 1024; off <<= 1){
      int t = (threadIdx.x >= off) ? sh[threadIdx.x-off] : 0;
      __syncthreads();
      sh[threadIdx.x] += t;
      __syncthreads();
    }
    if (i < NBK) bbase[i] = carry + sh[threadIdx.x] - v;
    __syncthreads();
    if (threadIdx.x == 0) carry += sh[1023];
    __syncthreads();
  }
}

// P3: partition edges into bucket regions (LDS cursors, no global atomics)
__global__ __launch_bounds__(512) void k_part(const int* __restrict__ src, const int* __restrict__ dst,
    const int* __restrict__ hist, const int* __restrict__ bbase, uint* __restrict__ ebuf){
  __shared__ int cur[NBK];
  int blk = blockIdx.x;
  for (int b = threadIdx.x; b < NBK; b += 512)
    cur[b] = hist[(size_t)blk*NBK + b] + bbase[b];
  __syncthreads();
  int beg = blk*EPB, end = beg + EPB;
  for (int i = beg + threadIdx.x; i < end; i += 512){
    int d = dst[i], s = src[i];
    int b = d >> 5;
    int p = atomicAdd(&cur[b], 1);              // LDS atomic
    ebuf[p] = (uint)s | ((uint)(d & 31) << 26);
  }
}

// P4: per-bucket counting sort by dst-low; writes rowptr AND col
__global__ __launch_bounds__(64) void k_fin(const uint* __restrict__ ebuf, const int* __restrict__ bbase,
    const int* __restrict__ bsum, int* __restrict__ rowptr, int* __restrict__ col){
  __shared__ int cnt32[32];
  __shared__ int exc[32];
  int b = blockIdx.x;
  int lane = threadIdx.x;
  if (lane < 32) cnt32[lane] = 0;
  __syncthreads();
  int base = bbase[b], n = bsum[b];
  for (int i = lane; i < n; i += 64)
    atomicAdd(&cnt32[ebuf[base+i] >> 26], 1);
  __syncthreads();
  if (lane == 0){
    int run = 0;
    for (int d = 0; d < 32; ++d){
      int t = cnt32[d];
      exc[d] = run;
      rowptr[b*32 + d] = base + run;
      run += t;
    }
  }
  __syncthreads();
  if (lane < 32) cnt32[lane] = exc[lane];       // reuse as cursors
  __syncthreads();
  for (int i = lane; i < n; i += 64){
    uint e = ebuf[base+i];
    int d = e >> 26;
    int r = atomicAdd(&cnt32[d], 1);
    col[base + r] = (int)(e & 0x03ffffffu);
  }
  if (b == 0 && lane == 0) rowptr[NN] = NE;
}

// ---------------- GAT1 linear (x@W1) + logits; writes bf16-packed feature table ----------------
__global__ __launch_bounds__(128) void k_lin1(const float* __restrict__ x, const float* __restrict__ W1,
    const float* __restrict__ as1, const float* __restrict__ ad1,
    uint* __restrict__ t1b, float* __restrict__ al_s, float* __restrict__ al_d){
  int n = blockIdx.x;
  int c = threadIdx.x;
  const float* xr = x + n*DI;
  float t = 0.f;
  #pragma unroll
  for (int k = 0; k < DI; ++k) t = fmaf(xr[k], W1[k*DD+c], t);
  uint mybf = f2bf(t);
  uint pbf  = (uint)__shfl_xor((int)mybf, 1, 64);
  if (!(c & 1)) t1b[(size_t)n*64 + (c>>1)] = mybf | (pbf<<16);
  float vs = t * as1[c];
  float vd = t * ad1[c];
  #pragma unroll
  for (int m = 8; m >= 1; m >>= 1){ vs += __shfl_xor(vs, m, 16); vd += __shfl_xor(vd, m, 16); }
  if ((c & 15) == 0){
    al_s[n*NH + (c>>4)] = vs;
    al_d[n*NH + (c>>4)] = vd;
  }
}

// ---------------- attn coeffs layer 1: wave per node, 8 edges x 8 heads per chunk ----------------
__global__ __launch_bounds__(256) void k_attn1(const float* __restrict__ al_s, const float* __restrict__ al_d,
    const int* __restrict__ rowptr, const int* __restrict__ col,
    float* __restrict__ alpha, float* __restrict__ a0n, float* __restrict__ invden){
  int n = blockIdx.x*4 + (threadIdx.x >> 6);
  if (n >= NN) return;
  int lane = threadIdx.x & 63;
  int h = lane & 7, j = lane >> 3;
  int beg = rowptr[n], end = rowptr[n+1];
  float ald = al_d[n*NH + h];
  float es = leaky(al_s[n*NH + h] + ald);       // self-loop
  float vmax = -3.4e38f;
  for (int e = beg + j; e < end; e += 8){
    int s = col[e];
    vmax = fmaxf(vmax, leaky(al_s[s*NH + h] + ald));
  }
  vmax = fmaxf(vmax, __shfl_xor(vmax, 8, 64));
  vmax = fmaxf(vmax, __shfl_xor(vmax, 16, 64));
  vmax = fmaxf(vmax, __shfl_xor(vmax, 32, 64));
  float m = fmaxf(es, vmax);
  float sl = 0.f;
  for (int e = beg + j; e < end; e += 8){
    int s = col[e];
    float a = __expf(leaky(al_s[s*NH + h] + ald) - m);
    alpha[(size_t)e*NH + h] = a;
    sl += a;
  }
  sl += __shfl_xor(sl, 8, 64);
  sl += __shfl_xor(sl, 16, 64);
  sl += __shfl_xor(sl, 32, 64);
  float a0 = __expf(es - m);
  float inv = 1.f/(a0 + sl + 1e-16f);
  if (j == 0){
    a0n[n*NH + h]    = a0*inv;
    invden[n*NH + h] = inv;
  }
}

// ---------------- GAT1 gather: wave per node, bf16 rows, 2ch/lane, + b1, ReLU ----------------
__global__ __launch_bounds__(256) void k_gat1g(const uint* __restrict__ t1b,
    const float* __restrict__ alpha, const float* __restrict__ a0n, const float* __restrict__ invden,
    const int* __restrict__ rowptr, const int* __restrict__ col,
    const float* __restrict__ b1, float* __restrict__ out){
  int n = blockIdx.x*4 + (threadIdx.x >> 6);
  if (n >= NN) return;
  int lane = threadIdx.x & 63;
  int h = lane >> 3;                  // head of channels (2*lane, 2*lane+1)
  int beg = rowptr[n], end = rowptr[n+1];
  float s0 = 0.f, s1 = 0.f;
  int e = beg;
  for (; e + 4 <= end; e += 4){
    int c0 = col[e], c1 = col[e+1], c2 = col[e+2], c3 = col[e+3];
    float a0_ = alpha[(size_t)e*NH + h];
    float a1_ = alpha[(size_t)(e+1)*NH + h];
    float a2_ = alpha[(size_t)(e+2)*NH + h];
    float a3_ = alpha[(size_t)(e+3)*NH + h];
    uint p0 = t1b[(size_t)c0*64 + lane];
    uint p1 = t1b[(size_t)c1*64 + lane];
    uint p2 = t1b[(size_t)c2*64 + lane];
    uint p3 = t1b[(size_t)c3*64 + lane];
    s0 = fmaf(a0_, bflo(p0), s0); s1 = fmaf(a0_, bfhi(p0), s1);
    s0 = fmaf(a1_, bflo(p1), s0); s1 = fmaf(a1_, bfhi(p1), s1);
    s0 = fmaf(a2_, bflo(p2), s0); s1 = fmaf(a2_, bfhi(p2), s1);
    s0 = fmaf(a3_, bflo(p3), s0); s1 = fmaf(a3_, bfhi(p3), s1);
  }
  for (; e < end; ++e){
    float a = alpha[(size_t)e*NH + h];
    uint p = t1b[(size_t)col[e]*64 + lane];
    s0 = fmaf(a, bflo(p), s0); s1 = fmaf(a, bfhi(p), s1);
  }
  uint ps = t1b[(size_t)n*64 + lane];
  float inv = invden[n*NH + h], az = a0n[n*NH + h];
  float2 bb = ((const float2*)b1)[lane];
  float r0 = fmaf(inv, s0, az*bflo(ps)) + bb.x;
  float r1 = fmaf(inv, s1, az*bfhi(ps)) + bb.y;
  ((float2*)out)[(size_t)n*64 + lane] = make_float2(fmaxf(r0,0.f), fmaxf(r1,0.f));
}

// ---------------- GAT2 attention logits from bf16 table ----------------
__global__ __launch_bounds__(256) void k_al2(const uint* __restrict__ t2b,
    const float* __restrict__ as2, const float* __restrict__ ad2,
    float* __restrict__ al_s, float* __restrict__ al_d){
  int n = blockIdx.x*4 + (threadIdx.x >> 6);
  if (n >= NN) return;
  int lane = threadIdx.x & 63;
  uint p = t2b[(size_t)n*64 + lane];
  float v0 = bflo(p), v1 = bfhi(p);
  float2 s2 = ((const float2*)as2)[lane];
  float2 d2 = ((const float2*)ad2)[lane];
  float vs = v0*s2.x + v1*s2.y;
  float vd = v0*d2.x + v1*d2.y;
  #pragma unroll
  for (int m = 32; m >= 1; m >>= 1){ vs += __shfl_xor(vs, m, 64); vd += __shfl_xor(vd, m, 64); }
  if (lane == 0){ al_s[n] = vs; al_d[n] = vd; }
}

// ---------------- attn coeffs layer 2: wave per node ----------------
__global__ __launch_bounds__(256) void k_attn2(const float* __restrict__ al_s, const float* __restrict__ al_d,
    const int* __restrict__ rowptr, const int* __restrict__ col,
    float* __restrict__ alpha, float* __restrict__ a0n, float* __restrict__ invden){
  int n = blockIdx.x*4 + (threadIdx.x >> 6);
  if (n >= NN) return;
  int lane = threadIdx.x & 63;
  int beg = rowptr[n], end = rowptr[n+1];
  float ald = al_d[n];
  float es = leaky(al_s[n] + ald);
  float vmax = -3.4e38f;
  for (int e = beg + lane; e < end; e += 64)
    vmax = fmaxf(vmax, leaky(al_s[col[e]] + ald));
  #pragma unroll
  for (int mk = 32; mk >= 1; mk >>= 1) vmax = fmaxf(vmax, __shfl_xor(vmax, mk, 64));
  float m = fmaxf(es, vmax);
  float sl = 0.f;
  for (int e = beg + lane; e < end; e += 64){
    float a = __expf(leaky(al_s[col[e]] + ald) - m);
    alpha[e] = a;
    sl += a;
  }
  #pragma unroll
  for (int mk = 32; mk >= 1; mk >>= 1) sl += __shfl_xor(sl, mk, 64);
  float a0 = __expf(es - m);
  float inv = 1.f/(a0 + sl + 1e-16f);
  if (lane == 0){ a0n[n] = a0*inv; invden[n] = inv; }
}

// ---------------- GAT2 gather: wave per node, bf16 rows, + b2 ----------------
__global__ __launch_bounds__(256) void k_gat2g(const uint* __restrict__ t2b,
    const float* __restrict__ alpha, const float* __restrict__ a0n, const float* __restrict__ invden,
    const int* __restrict__ rowptr, const int* __restrict__ col,
    const float* __restrict__ b2, float* __restrict__ out){
  int n = blockIdx.x*4 + (threadIdx.x >> 6);
  if (n >= NN) return;
  int lane = threadIdx.x & 63;
  int beg = rowptr[n], end = rowptr[n+1];
  float s0 = 0.f, s1 = 0.f;
  int e = beg;
  for (; e + 4 <= end; e += 4){
    int c0 = col[e], c1 = col[e+1], c2 = col[e+2], c3 = col[e+3];
    float a0_ = alpha[e],   a1_ = alpha[e+1];
    float a2_ = alpha[e+2], a3_ = alpha[e+3];
    uint p0 = t2b[(size_t)c0*64 + lane];
    uint p1 = t2b[(size_t)c1*64 + lane];
    uint p2 = t2b[(size_t)c2*64 + lane];
    uint p3 = t2b[(size_t)c3*64 + lane];
    s0 = fmaf(a0_, bflo(p0), s0); s1 = fmaf(a0_, bfhi(p0), s1);
    s0 = fmaf(a1_, bflo(p1), s0); s1 = fmaf(a1_, bfhi(p1), s1);
    s0 = fmaf(a2_, bflo(p2), s0); s1 = fmaf(a2_, bfhi(p2), s1);
    s0 = fmaf(a3_, bflo(p3), s0); s1 = fmaf(a3_, bfhi(p3), s1);
  }
  for (; e < end; ++e){
    float a = alpha[e];
    uint p = t2b[(size_t)col[e]*64 + lane];
    s0 = fmaf(a, bflo(p), s0); s1 = fmaf(a, bfhi(p), s1);
  }
  uint ps = t2b[(size_t)n*64 + lane];
  float inv = invden[n], az = a0n[n];
  float2 bb = ((const float2*)b2)[lane];
  float r0 = fmaf(inv, s0, az*bflo(ps)) + bb.x;
  float r1 = fmaf(inv, s1, az*bfhi(ps)) + bb.y;
  ((float2*)out)[(size_t)n*64 + lane] = make_float2(r0, r1);
}

// ---------------- 128x128 GEMM, register-tiled; fp32 and/or packed-bf16 output ----------------
template<bool RELU, bool BIAS, bool RES, bool F32OUT, bool BF16OUT>
__global__ __launch_bounds__(256) void k_gemm128(const float* __restrict__ X, const float* __restrict__ W,
    const float* __restrict__ bias, const float* __restrict__ res, float* __restrict__ out,
    uint* __restrict__ outb, int nrows){
  __shared__ __align__(16) float Xs[DD][132];   // [k][r], padded rows
  int tid = threadIdx.x;
  int n0 = blockIdx.x * 128;
  {
    int r  = tid >> 1;
    int c0 = (tid & 1) * 64;
    int n  = n0 + r;
    if (n < nrows){
      const float* xp = X + (size_t)n*DD + c0;
      #pragma unroll
      for (int i = 0; i < 16; ++i){
        float4 v = *(const float4*)(xp + i*4);
        int c = c0 + i*4;
        Xs[c][r] = v.x; Xs[c+1][r] = v.y; Xs[c+2][r] = v.z; Xs[c+3][r] = v.w;
      }
    } else {
      #pragma unroll
      for (int i = 0; i < 16; ++i){
        int c = c0 + i*4;
        Xs[c][r] = 0.f; Xs[c+1][r] = 0.f; Xs[c+2][r] = 0.f; Xs[c+3][r] = 0.f;
      }
    }
  }
  __syncthreads();
  int tc = tid & 31, tr = tid >> 5;
  int j0 = tc*4, r0 = tr*16;
  float4 acc[16];
  #pragma unroll
  for (int i = 0; i < 16; ++i) acc[i] = make_float4(0.f,0.f,0.f,0.f);
  #pragma unroll 2
  for (int k = 0; k < DD; ++k){
    float4 w4 = *(const float4*)(W + k*DD + j0);
    #pragma unroll
    for (int ii = 0; ii < 4; ++ii){
      float4 x4 = *(const float4*)&Xs[k][r0 + ii*4];
      float xs[4] = {x4.x, x4.y, x4.z, x4.w};
      #pragma unroll
      for (int jj = 0; jj < 4; ++jj){
        float xv = xs[jj];
        float4& a = acc[ii*4+jj];
        a.x = fmaf(xv, w4.x, a.x);
        a.y = fmaf(xv, w4.y, a.y);
        a.z = fmaf(xv, w4.z, a.z);
        a.w = fmaf(xv, w4.w, a.w);
      }
    }
  }
  float4 b4 = make_float4(0.f,0.f,0.f,0.f);
  if (BIAS) b4 = *(const float4*)(bias + j0);
  #pragma unroll
  for (int i = 0; i < 16; ++i){
    int n = n0 + r0 + i;
    if (n >= nrows) break;
    float4 v = acc[i];
    if (BIAS){ v.x += b4.x; v.y += b4.y; v.z += b4.z; v.w += b4.w; }
    if (RES){
      float4 rv = *(const float4*)(res + (size_t)n*DD + j0);
      v.x += rv.x; v.y += rv.y; v.z += rv.z; v.w += rv.w;
    }
    if (RELU){ v.x = fmaxf(v.x,0.f); v.y = fmaxf(v.y,0.f); v.z = fmaxf(v.z,0.f); v.w = fmaxf(v.w,0.f); }
    if (F32OUT) *(float4*)(out + (size_t)n*DD + j0) = v;
    if (BF16OUT){
      uint2 pk;
      pk.x = f2bf(v.x) | (f2bf(v.y)<<16);
      pk.y = f2bf(v.z) | (f2bf(v.w)<<16);
      *(uint2*)(outb + (size_t)n*64 + (j0>>1)) = pk;
    }
  }
}

// ---------------- graph LayerNorm (scalar mean/var over N*D) ----------------
__global__ __launch_bounds__(256) void k_ln_reduce(const float* __restrict__ x, float* __restrict__ pbuf){
  const float4* x4 = (const float4*)x;
  const int n4 = NN*DD/4;
  float s = 0.f, ss = 0.f;
  for (int i = blockIdx.x*256 + threadIdx.x; i < n4; i += gridDim.x*256){
    float4 v = x4[i];
    s  += v.x + v.y + v.z + v.w;
    ss += v.x*v.x + v.y*v.y + v.z*v.z + v.w*v.w;
  }
  #pragma unroll
  for (int m = 32; m >= 1; m >>= 1){ s += __shfl_xor(s, m, 64); ss += __shfl_xor(ss, m, 64); }
  __shared__ float sh[8];
  int wid = threadIdx.x >> 6, lane = threadIdx.x & 63;
  if (lane == 0){ sh[wid*2] = s; sh[wid*2+1] = ss; }
  __syncthreads();
  if (threadIdx.x == 0){
    float S = 0.f, SS = 0.f;
    for (int w = 0; w < 4; ++w){ S += sh[2*w]; SS += sh[2*w+1]; }
    pbuf[blockIdx.x*2] = S; pbuf[blockIdx.x*2+1] = SS;
  }
}

__global__ __launch_bounds__(256) void k_ln_stats(const float* __restrict__ pbuf, float* __restrict__ stats, int nb){
  float s = 0.f, ss = 0.f;
  for (int i = threadIdx.x; i < nb; i += 256){ s += pbuf[2*i]; ss += pbuf[2*i+1]; }
  #pragma unroll
  for (int m = 32; m >= 1; m >>= 1){ s += __shfl_xor(s, m, 64); ss += __shfl_xor(ss, m, 64); }
  __shared__ float sh[8];
  int wid = threadIdx.x >> 6, lane = threadIdx.x & 63;
  if (lane == 0){ sh[wid*2] = s; sh[wid*2+1] = ss; }
  __syncthreads();
  if (threadIdx.x == 0){
    float S = 0.f, SS = 0.f;
    for (int w = 0; w < 4; ++w){ S += sh[2*w]; SS += sh[2*w+1]; }
    const float inv = 1.f/((float)NN*(float)DD);
    float mu = S*inv;
    float var = SS*inv - mu*mu;
    stats[0] = mu;
    stats[1] = rsqrtf(var + 1e-5f);
  }
}

__global__ __launch_bounds__(256) void k_ln_apply(float* __restrict__ x, const float* __restrict__ g,
    const float* __restrict__ be, const float* __restrict__ stats){
  const int n4 = NN*DD/4;
  float mu = stats[0], rs = stats[1];
  float4* x4 = (float4*)x;
  const float4* g4p = (const float4*)g;
  const float4* b4p = (const float4*)be;
  for (int i = blockIdx.x*256 + threadIdx.x; i < n4; i += gridDim.x*256){
    int c4 = i & 31;
    float4 v = x4[i]; float4 gg = g4p[c4]; float4 bb = b4p[c4];
    v.x = (v.x - mu)*rs*gg.x + bb.x;
    v.y = (v.y - mu)*rs*gg.y + bb.y;
    v.z = (v.z - mu)*rs*gg.z + bb.z;
    v.w = (v.w - mu)*rs*gg.w + bb.w;
    x4[i] = v;
  }
}

// ---------------- final projection: val[n] = h[n].fcw + fcb ----------------
__global__ __launch_bounds__(256) void k_fdot(const float* __restrict__ h, const float* __restrict__ fw,
    const float* __restrict__ fb, float* __restrict__ val){
  int n = blockIdx.x*4 + (threadIdx.x >> 6);
  if (n >= NN) return;
  int lane = threadIdx.x & 63;
  const float* r = h + (size_t)n*DD;
  float v = r[lane]*fw[lane] + r[lane+64]*fw[lane+64];
  #pragma unroll
  for (int m = 32; m >= 1; m >>= 1) v += __shfl_xor(v, m, 64);
  if (lane == 0) val[n] = v + fb[0];
}

// ---------------- segment mean over sorted batch: one wave per graph ----------------
__global__ __launch_bounds__(64) void k_pool(const float* __restrict__ val, const int* __restrict__ batch,
                                             float* __restrict__ out){
  int g = blockIdx.x;
  int lane = threadIdx.x;
  int lo = 0, hi = NN;
  while (lo < hi){ int mid = (lo+hi)>>1; if (batch[mid] < g) lo = mid+1; else hi = mid; }
  int start = lo;
  hi = NN;
  while (lo < hi){ int mid = (lo+hi)>>1; if (batch[mid] < g+1) lo = mid+1; else hi = mid; }
  int end = lo;
  float s = 0.f;
  for (int i = start + lane; i < end; i += 64) s += val[i];
  #pragma unroll
  for (int m = 32; m >= 1; m >>= 1) s += __shfl_xor(s, m, 64);
  if (lane == 0) out[g] = s / fmaxf((float)(end - start), 1.f);
}

extern "C" void kernel_launch(void* const* d_in, const int* in_sizes, int n_in,
                              void* d_out, int out_size, void* d_ws, size_t ws_size,
                              hipStream_t stream){
  const float* x   = (const float*)d_in[0];
  const int*   ei  = (const int*)d_in[1];
  const int* batch = (const int*)d_in[2];
  const float* W1  = (const float*)d_in[3];
  const float* as1 = (const float*)d_in[4];
  const float* ad1 = (const float*)d_in[5];
  const float* b1  = (const float*)d_in[6];
  const float* W2  = (const float*)d_in[7];
  const float* as2 = (const float*)d_in[8];
  const float* ad2 = (const float*)d_in[9];
  const float* b2  = (const float*)d_in[10];
  const float* fc1w= (const float*)d_in[11];
  const float* fc1b= (const float*)d_in[12];
  const float* fc2w= (const float*)d_in[13];
  const float* fc2b= (const float*)d_in[14];
  const float* fc3w= (const float*)d_in[15];
  const float* fc3b= (const float*)d_in[16];
  const float* fc4w= (const float*)d_in[17];
  const float* fc4b= (const float*)d_in[18];
  const float* g1  = (const float*)d_in[19];
  const float* be1 = (const float*)d_in[20];
  const float* g2  = (const float*)d_in[21];
  const float* be2 = (const float*)d_in[22];
  const float* fcw = (const float*)d_in[23];
  const float* fcb = (const float*)d_in[24];
  float* out = (float*)d_out;
  (void)in_sizes; (void)n_in; (void)out_size; (void)ws_size;

  char* ws = (char*)d_ws;
  size_t off = 0;
  auto alloc = [&](size_t bytes)->void*{
    void* p = ws + off;
    off += (bytes + 255) & ~(size_t)255;
    return p;
  };
  float* A    = (float*)alloc((size_t)NN*DD*4);   // aliases: hist (CSR build), t1b/t2b (bf16 tables)
  float* B    = (float*)alloc((size_t)NN*DD*4);
  float* C    = (float*)alloc((size_t)NN*DD*4);   // alias: alpha1 [E,8] during layer-1 GAT
  float* als1 = (float*)alloc((size_t)NN*NH*4);
  float* ald1 = (float*)alloc((size_t)NN*NH*4);
  float* a0n1 = (float*)alloc((size_t)NN*NH*4);
  float* inv1 = (float*)alloc((size_t)NN*NH*4);
  float* als2 = (float*)alloc((size_t)NN*4);
  float* ald2 = (float*)alloc((size_t)NN*4);
  float* a0n2 = (float*)alloc((size_t)NN*4);
  float* inv2 = (float*)alloc((size_t)NN*4);
  float* alpha2 = (float*)alloc((size_t)NE*4);    // alias: ebuf during CSR build
  int*   rowptr = (int*)alloc((size_t)(NN+1)*4);
  int*   col    = (int*)alloc((size_t)NE*4);
  int*   bsum   = (int*)alloc((size_t)NBK*4);
  int*   bbase  = (int*)alloc((size_t)NBK*4);
  float* pbuf   = (float*)alloc(1024*2*4);
  float* stats  = (float*)alloc(2*4);
  float* val    = (float*)alloc((size_t)NN*4);

  float* alpha1 = C;            // C dead until fc2 output
  uint*  t1b    = (uint*)A;     // A dead until fc1 output
  uint*  t2b    = (uint*)A;     // A dead again after fc2 consumes it
  int*   hist   = (int*)A;      // A dead during CSR build (NBLK*NBK ints = 3.2MB << 51MB)
  uint*  ebuf   = (uint*)alpha2;// alpha2 first written after CSR build completes

  const int* esrc = ei;
  const int* edst = ei + NE;

  // ---- CSR build (atomic-free partition; subsumes count+scan+fill) ----
  k_hist <<<NBLK, 512, 0, stream>>>(edst, hist);
  k_bsum <<<(NBK+255)/256, 256, 0, stream>>>(hist, bsum);
  k_bscan<<<1, 1024, 0, stream>>>(bsum, bbase);
  k_part <<<NBLK, 512, 0, stream>>>(esrc, edst, hist, bbase, ebuf);
  k_fin  <<<NBK, 64, 0, stream>>>(ebuf, bbase, bsum, rowptr, col);

  const int WB = (NN + 3)/4;   // wave-per-node kernels, 4 waves/block

  // GAT layer 1 (bf16 feature table)
  k_lin1<<<NN, 128, 0, stream>>>(x, W1, as1, ad1, t1b, als1, ald1);
  k_attn1<<<WB, 256, 0, stream>>>(als1, ald1, rowptr, col, alpha1, a0n1, inv1);
  k_gat1g<<<WB, 256, 0, stream>>>(t1b, alpha1, a0n1, inv1, rowptr, col, b1, B);

  const int GB = (NN + 127)/128;
  // fc1 (relu), fc2 (+res h1, relu)
  k_gemm128<true,  true, false, true, false><<<GB, 256, 0, stream>>>(B, fc1w, fc1b, nullptr, A, nullptr, NN);
  k_gemm128<true,  true, true,  true, false><<<GB, 256, 0, stream>>>(A, fc2w, fc2b, B,       C, nullptr, NN);

  // LN1 (graph mode)
  k_ln_reduce<<<1024, 256, 0, stream>>>(C, pbuf);
  k_ln_stats<<<1, 256, 0, stream>>>(pbuf, stats, 1024);
  k_ln_apply<<<1024, 256, 0, stream>>>(C, g1, be1, stats);

  // GAT layer 2: t2b = bf16(C @ W2)
  k_gemm128<false, false, false, false, true><<<GB, 256, 0, stream>>>(C, W2, nullptr, nullptr, nullptr, t2b, NN);
  k_al2<<<WB, 256, 0, stream>>>(t2b, as2, ad2, als2, ald2);
  k_attn2<<<WB, 256, 0, stream>>>(als2, ald2, rowptr, col, alpha2, a0n2, inv2);
  k_gat2g<<<WB, 256, 0, stream>>>(t2b, alpha2, a0n2, inv2, rowptr, col, b2, B);

  // fc3 (relu), fc4 (+res C, no relu)
  k_gemm128<true,  true, false, true, false><<<GB, 256, 0, stream>>>(B, fc3w, fc3b, nullptr, A, nullptr, NN);
  k_gemm128<false, true, true,  true, false><<<GB, 256, 0, stream>>>(A, fc4w, fc4b, C,       B, nullptr, NN);

  // LN2
  k_ln_reduce<<<1024, 256, 0, stream>>>(B, pbuf);
  k_ln_stats<<<1, 256, 0, stream>>>(pbuf, stats, 1024);
  k_ln_apply<<<1024, 256, 0, stream>>>(B, g2, be2, stats);

  // final projection + global mean pool per graph (no atomics)
  k_fdot<<<WB, 256, 0, stream>>>(B, fcw, fcb, val);
  k_pool<<<NG, 64, 0, stream>>>(val, batch, out);
}

// Round 6
// 561.347 us; speedup vs baseline: 2.3835x; 1.3585x over previous
//
#include <hip/hip_runtime.h>
#include <cstdint>

#define NN 100000
#define NE 1600000
#define DI 9
#define DD 128
#define NH 8
#define NG 1000

#define NBK 3125            // buckets = dst>>5; 3125*32 == 100000 exactly
#define NBLK 256            // partition blocks
#define EPB (NE/NBLK)       // 6250 edges per block (exact)

typedef unsigned int uint;
typedef __attribute__((ext_vector_type(8))) short bf16x8;
typedef __attribute__((ext_vector_type(4))) float f32x4;

__device__ __forceinline__ float leaky(float x){ return x > 0.f ? x : 0.2f*x; }
__device__ __forceinline__ uint f2bf(float f){            // round-to-nearest-even bf16
  uint u = __float_as_uint(f);
  return (u + 0x7fffu + ((u>>16)&1u)) >> 16;
}
__device__ __forceinline__ float bflo(uint p){ return __uint_as_float(p << 16); }
__device__ __forceinline__ float bfhi(uint p){ return __uint_as_float(p & 0xffff0000u); }
__device__ __forceinline__ uint packbf(float a, float b){ return f2bf(a) | (f2bf(b)<<16); }

union U16 { uint4 u; bf16x8 v; };
__device__ __forceinline__ bf16x8 ld8(const uint* p){ U16 t; t.u = *(const uint4*)p; return t.v; }

// ================= CSR build: atomic-free bucket partition =================
__global__ __launch_bounds__(512) void k_hist(const int* __restrict__ dst, int* __restrict__ hist){
  __shared__ int h[NBK];
  for (int i = threadIdx.x; i < NBK; i += 512) h[i] = 0;
  __syncthreads();
  int blk = blockIdx.x;
  int beg = blk*EPB, end = beg + EPB;
  for (int i = beg + threadIdx.x; i < end; i += 512)
    atomicAdd(&h[dst[i] >> 5], 1);
  __syncthreads();
  for (int b = threadIdx.x; b < NBK; b += 512) hist[(size_t)blk*NBK + b] = h[b];
}

__global__ __launch_bounds__(256) void k_bsum(int* __restrict__ hist, int* __restrict__ bsum){
  int b = blockIdx.x*256 + threadIdx.x;
  if (b >= NBK) return;
  int run = 0;
  for (int k = 0; k < NBLK; ++k){
    int t = hist[(size_t)k*NBK + b];
    hist[(size_t)k*NBK + b] = run;
    run += t;
  }
  bsum[b] = run;
}

__global__ __launch_bounds__(1024) void k_bscan(const int* __restrict__ bsum, int* __restrict__ bbase){
  __shared__ int sh[1024];
  __shared__ int carry;
  if (threadIdx.x == 0) carry = 0;
  __syncthreads();
  for (int c0 = 0; c0 < NBK; c0 += 1024){
    int i = c0 + threadIdx.x;
    int v = (i < NBK) ? bsum[i] : 0;
    sh[threadIdx.x] = v;
    __syncthreads();
    for (int off = 1; off < 1024; off <<= 1){
      int t = (threadIdx.x >= off) ? sh[threadIdx.x-off] : 0;
      __syncthreads();
      sh[threadIdx.x] += t;
      __syncthreads();
    }
    if (i < NBK) bbase[i] = carry + sh[threadIdx.x] - v;
    __syncthreads();
    if (threadIdx.x == 0) carry += sh[1023];
    __syncthreads();
  }
}

__global__ __launch_bounds__(512) void k_part(const int* __restrict__ src, const int* __restrict__ dst,
    const int* __restrict__ hist, const int* __restrict__ bbase, uint* __restrict__ ebuf){
  __shared__ int cur[NBK];
  int blk = blockIdx.x;
  for (int b = threadIdx.x; b < NBK; b += 512)
    cur[b] = hist[(size_t)blk*NBK + b] + bbase[b];
  __syncthreads();
  int beg = blk*EPB, end = beg + EPB;
  for (int i = beg + threadIdx.x; i < end; i += 512){
    int d = dst[i], s = src[i];
    int b = d >> 5;
    int p = atomicAdd(&cur[b], 1);              // LDS atomic
    ebuf[p] = (uint)s | ((uint)(d & 31) << 26);
  }
}

__global__ __launch_bounds__(64) void k_fin(const uint* __restrict__ ebuf, const int* __restrict__ bbase,
    const int* __restrict__ bsum, int* __restrict__ rowptr, int* __restrict__ col){
  __shared__ int cnt32[32];
  __shared__ int exc[32];
  int b = blockIdx.x;
  int lane = threadIdx.x;
  if (lane < 32) cnt32[lane] = 0;
  __syncthreads();
  int base = bbase[b], n = bsum[b];
  for (int i = lane; i < n; i += 64)
    atomicAdd(&cnt32[ebuf[base+i] >> 26], 1);
  __syncthreads();
  if (lane == 0){
    int run = 0;
    for (int d = 0; d < 32; ++d){
      int t = cnt32[d];
      exc[d] = run;
      rowptr[b*32 + d] = base + run;
      run += t;
    }
  }
  __syncthreads();
  if (lane < 32) cnt32[lane] = exc[lane];
  __syncthreads();
  for (int i = lane; i < n; i += 64){
    uint e = ebuf[base+i];
    int d = e >> 26;
    int r = atomicAdd(&cnt32[d], 1);
    col[base + r] = (int)(e & 0x03ffffffu);
  }
  if (b == 0 && lane == 0) rowptr[NN] = NE;
}

// ---------------- weight convert: WT_bf16[n][k] packed, from W[k][n] f32 ----------------
__global__ __launch_bounds__(64) void k_wconv(const float* __restrict__ W, uint* __restrict__ WT){
  int n = blockIdx.x;            // output row (column of W)
  int t = threadIdx.x;           // covers k = 2t, 2t+1
  float w0 = W[(2*t)*DD + n];
  float w1 = W[(2*t+1)*DD + n];
  WT[n*64 + t] = packbf(w0, w1);
}

// ---------------- GAT1 linear (x@W1) + logits; writes bf16-packed feature table ----------------
__global__ __launch_bounds__(128) void k_lin1(const float* __restrict__ x, const float* __restrict__ W1,
    const float* __restrict__ as1, const float* __restrict__ ad1,
    uint* __restrict__ t1b, float* __restrict__ al_s, float* __restrict__ al_d){
  int n = blockIdx.x;
  int c = threadIdx.x;
  const float* xr = x + n*DI;
  float t = 0.f;
  #pragma unroll
  for (int k = 0; k < DI; ++k) t = fmaf(xr[k], W1[k*DD+c], t);
  uint mybf = f2bf(t);
  uint pbf  = (uint)__shfl_xor((int)mybf, 1, 64);
  if (!(c & 1)) t1b[(size_t)n*64 + (c>>1)] = mybf | (pbf<<16);
  float vs = t * as1[c];
  float vd = t * ad1[c];
  #pragma unroll
  for (int m = 8; m >= 1; m >>= 1){ vs += __shfl_xor(vs, m, 16); vd += __shfl_xor(vd, m, 16); }
  if ((c & 15) == 0){
    al_s[n*NH + (c>>4)] = vs;
    al_d[n*NH + (c>>4)] = vd;
  }
}

// ---------------- attn coeffs layer 1 ----------------
__global__ __launch_bounds__(256) void k_attn1(const float* __restrict__ al_s, const float* __restrict__ al_d,
    const int* __restrict__ rowptr, const int* __restrict__ col,
    float* __restrict__ alpha, float* __restrict__ a0n, float* __restrict__ invden){
  int n = blockIdx.x*4 + (threadIdx.x >> 6);
  if (n >= NN) return;
  int lane = threadIdx.x & 63;
  int h = lane & 7, j = lane >> 3;
  int beg = rowptr[n], end = rowptr[n+1];
  float ald = al_d[n*NH + h];
  float es = leaky(al_s[n*NH + h] + ald);       // self-loop
  float vmax = -3.4e38f;
  for (int e = beg + j; e < end; e += 8){
    int s = col[e];
    vmax = fmaxf(vmax, leaky(al_s[s*NH + h] + ald));
  }
  vmax = fmaxf(vmax, __shfl_xor(vmax, 8, 64));
  vmax = fmaxf(vmax, __shfl_xor(vmax, 16, 64));
  vmax = fmaxf(vmax, __shfl_xor(vmax, 32, 64));
  float m = fmaxf(es, vmax);
  float sl = 0.f;
  for (int e = beg + j; e < end; e += 8){
    int s = col[e];
    float a = __expf(leaky(al_s[s*NH + h] + ald) - m);
    alpha[(size_t)e*NH + h] = a;
    sl += a;
  }
  sl += __shfl_xor(sl, 8, 64);
  sl += __shfl_xor(sl, 16, 64);
  sl += __shfl_xor(sl, 32, 64);
  float a0 = __expf(es - m);
  float inv = 1.f/(a0 + sl + 1e-16f);
  if (j == 0){
    a0n[n*NH + h]    = a0*inv;
    invden[n*NH + h] = inv;
  }
}

// ---------------- GAT1 gather: bf16 rows, 2ch/lane, + b1, ReLU, bf16 out ----------------
__global__ __launch_bounds__(256) void k_gat1g(const uint* __restrict__ t1b,
    const float* __restrict__ alpha, const float* __restrict__ a0n, const float* __restrict__ invden,
    const int* __restrict__ rowptr, const int* __restrict__ col,
    const float* __restrict__ b1, uint* __restrict__ outb){
  int n = blockIdx.x*4 + (threadIdx.x >> 6);
  if (n >= NN) return;
  int lane = threadIdx.x & 63;
  int h = lane >> 3;
  int beg = rowptr[n], end = rowptr[n+1];
  float s0 = 0.f, s1 = 0.f;
  int e = beg;
  for (; e + 4 <= end; e += 4){
    int c0 = col[e], c1 = col[e+1], c2 = col[e+2], c3 = col[e+3];
    float a0_ = alpha[(size_t)e*NH + h];
    float a1_ = alpha[(size_t)(e+1)*NH + h];
    float a2_ = alpha[(size_t)(e+2)*NH + h];
    float a3_ = alpha[(size_t)(e+3)*NH + h];
    uint p0 = t1b[(size_t)c0*64 + lane];
    uint p1 = t1b[(size_t)c1*64 + lane];
    uint p2 = t1b[(size_t)c2*64 + lane];
    uint p3 = t1b[(size_t)c3*64 + lane];
    s0 = fmaf(a0_, bflo(p0), s0); s1 = fmaf(a0_, bfhi(p0), s1);
    s0 = fmaf(a1_, bflo(p1), s0); s1 = fmaf(a1_, bfhi(p1), s1);
    s0 = fmaf(a2_, bflo(p2), s0); s1 = fmaf(a2_, bfhi(p2), s1);
    s0 = fmaf(a3_, bflo(p3), s0); s1 = fmaf(a3_, bfhi(p3), s1);
  }
  for (; e < end; ++e){
    float a = alpha[(size_t)e*NH + h];
    uint p = t1b[(size_t)col[e]*64 + lane];
    s0 = fmaf(a, bflo(p), s0); s1 = fmaf(a, bfhi(p), s1);
  }
  uint ps = t1b[(size_t)n*64 + lane];
  float inv = invden[n*NH + h], az = a0n[n*NH + h];
  float2 bb = ((const float2*)b1)[lane];
  float r0 = fmaf(inv, s0, az*bflo(ps)) + bb.x;
  float r1 = fmaf(inv, s1, az*bfhi(ps)) + bb.y;
  outb[(size_t)n*64 + lane] = packbf(fmaxf(r0,0.f), fmaxf(r1,0.f));
}

// ---------------- GAT2 attention logits from bf16 table ----------------
__global__ __launch_bounds__(256) void k_al2(const uint* __restrict__ t2b,
    const float* __restrict__ as2, const float* __restrict__ ad2,
    float* __restrict__ al_s, float* __restrict__ al_d){
  int n = blockIdx.x*4 + (threadIdx.x >> 6);
  if (n >= NN) return;
  int lane = threadIdx.x & 63;
  uint p = t2b[(size_t)n*64 + lane];
  float v0 = bflo(p), v1 = bfhi(p);
  float2 s2 = ((const float2*)as2)[lane];
  float2 d2 = ((const float2*)ad2)[lane];
  float vs = v0*s2.x + v1*s2.y;
  float vd = v0*d2.x + v1*d2.y;
  #pragma unroll
  for (int m = 32; m >= 1; m >>= 1){ vs += __shfl_xor(vs, m, 64); vd += __shfl_xor(vd, m, 64); }
  if (lane == 0){ al_s[n] = vs; al_d[n] = vd; }
}

// ---------------- attn coeffs layer 2 ----------------
__global__ __launch_bounds__(256) void k_attn2(const float* __restrict__ al_s, const float* __restrict__ al_d,
    const int* __restrict__ rowptr, const int* __restrict__ col,
    float* __restrict__ alpha, float* __restrict__ a0n, float* __restrict__ invden){
  int n = blockIdx.x*4 + (threadIdx.x >> 6);
  if (n >= NN) return;
  int lane = threadIdx.x & 63;
  int beg = rowptr[n], end = rowptr[n+1];
  float ald = al_d[n];
  float es = leaky(al_s[n] + ald);
  float vmax = -3.4e38f;
  for (int e = beg + lane; e < end; e += 64)
    vmax = fmaxf(vmax, leaky(al_s[col[e]] + ald));
  #pragma unroll
  for (int mk = 32; mk >= 1; mk >>= 1) vmax = fmaxf(vmax, __shfl_xor(vmax, mk, 64));
  float m = fmaxf(es, vmax);
  float sl = 0.f;
  for (int e = beg + lane; e < end; e += 64){
    float a = __expf(leaky(al_s[col[e]] + ald) - m);
    alpha[e] = a;
    sl += a;
  }
  #pragma unroll
  for (int mk = 32; mk >= 1; mk >>= 1) sl += __shfl_xor(sl, mk, 64);
  float a0 = __expf(es - m);
  float inv = 1.f/(a0 + sl + 1e-16f);
  if (lane == 0){ a0n[n] = a0*inv; invden[n] = inv; }
}

// ---------------- GAT2 gather: bf16 rows, + b2, bf16 out ----------------
__global__ __launch_bounds__(256) void k_gat2g(const uint* __restrict__ t2b,
    const float* __restrict__ alpha, const float* __restrict__ a0n, const float* __restrict__ invden,
    const int* __restrict__ rowptr, const int* __restrict__ col,
    const float* __restrict__ b2, uint* __restrict__ outb){
  int n = blockIdx.x*4 + (threadIdx.x >> 6);
  if (n >= NN) return;
  int lane = threadIdx.x & 63;
  int beg = rowptr[n], end = rowptr[n+1];
  float s0 = 0.f, s1 = 0.f;
  int e = beg;
  for (; e + 4 <= end; e += 4){
    int c0 = col[e], c1 = col[e+1], c2 = col[e+2], c3 = col[e+3];
    float a0_ = alpha[e],   a1_ = alpha[e+1];
    float a2_ = alpha[e+2], a3_ = alpha[e+3];
    uint p0 = t2b[(size_t)c0*64 + lane];
    uint p1 = t2b[(size_t)c1*64 + lane];
    uint p2 = t2b[(size_t)c2*64 + lane];
    uint p3 = t2b[(size_t)c3*64 + lane];
    s0 = fmaf(a0_, bflo(p0), s0); s1 = fmaf(a0_, bfhi(p0), s1);
    s0 = fmaf(a1_, bflo(p1), s0); s1 = fmaf(a1_, bfhi(p1), s1);
    s0 = fmaf(a2_, bflo(p2), s0); s1 = fmaf(a2_, bfhi(p2), s1);
    s0 = fmaf(a3_, bflo(p3), s0); s1 = fmaf(a3_, bfhi(p3), s1);
  }
  for (; e < end; ++e){
    float a = alpha[e];
    uint p = t2b[(size_t)col[e]*64 + lane];
    s0 = fmaf(a, bflo(p), s0); s1 = fmaf(a, bfhi(p), s1);
  }
  uint ps = t2b[(size_t)n*64 + lane];
  float inv = invden[n], az = a0n[n];
  float2 bb = ((const float2*)b2)[lane];
  float r0 = fmaf(inv, s0, az*bflo(ps)) + bb.x;
  float r1 = fmaf(inv, s1, az*bfhi(ps)) + bb.y;
  outb[(size_t)n*64 + lane] = packbf(r0, r1);
}

// ---------------- MFMA bf16 GEMM: [M,128]x[128,128], LDS-free, fused epilogue ----------------
// A frag: lane holds X[m0 + (lane&15)][k = 32*kk + (lane>>4)*8 + j]   (8 contiguous bf16)
// B frag: lane holds W[k][n0c + (lane&15)] = WT[n0c+(lane&15)][k...]  (8 contiguous bf16)
// C/D:    lane reg r holds OUT[m0 + (lane>>4)*4 + r][n0c + (lane&15)] (m89-verified)
template<bool RELU, bool BIAS, bool RES>
__global__ __launch_bounds__(256) void k_mfma(const uint* __restrict__ Xb, const uint* __restrict__ WTb,
    const float* __restrict__ bias, const uint* __restrict__ resb, uint* __restrict__ outb, int nrows){
  int lane = threadIdx.x & 63;
  int wid  = threadIdx.x >> 6;
  int m0 = blockIdx.x*128 + wid*32;
  int lr = lane & 15, hi4 = lane >> 4;
  f32x4 acc[2][8];
  #pragma unroll
  for (int a = 0; a < 2; ++a)
    #pragma unroll
    for (int c = 0; c < 8; ++c) acc[a][c] = (f32x4){0.f,0.f,0.f,0.f};
  int ra0 = m0 + lr;      if (ra0 > NN-1) ra0 = NN-1;
  int ra1 = m0 + 16 + lr; if (ra1 > NN-1) ra1 = NN-1;
  #pragma unroll
  for (int kk = 0; kk < 4; ++kk){
    int ko = kk*16 + hi4*4;                 // uint offset within row (32 bf16 per kk)
    bf16x8 a0 = ld8(Xb + (size_t)ra0*64 + ko);
    bf16x8 a1 = ld8(Xb + (size_t)ra1*64 + ko);
    #pragma unroll
    for (int c = 0; c < 8; ++c){
      bf16x8 b = ld8(WTb + (size_t)(c*16 + lr)*64 + ko);
      acc[0][c] = __builtin_amdgcn_mfma_f32_16x16x32_bf16(a0, b, acc[0][c], 0, 0, 0);
      acc[1][c] = __builtin_amdgcn_mfma_f32_16x16x32_bf16(a1, b, acc[1][c], 0, 0, 0);
    }
  }
  bool evn = !(lane & 1);
  int cph = lr >> 1;
  #pragma unroll
  for (int rg = 0; rg < 2; ++rg){
    #pragma unroll
    for (int c = 0; c < 8; ++c){
      int cp = c*8 + cph;
      #pragma unroll
      for (int r = 0; r < 4; ++r){
        float v0 = acc[rg][c][r];
        float v1 = __shfl_xor(v0, 1, 64);   // partner lane holds col+1 (even lanes use it)
        int row = m0 + rg*16 + hi4*4 + r;
        if (evn && row < nrows){
          if (BIAS){ float2 bb = ((const float2*)bias)[cp]; v0 += bb.x; v1 += bb.y; }
          if (RES){ uint rr = resb[(size_t)row*64 + cp]; v0 += bflo(rr); v1 += bfhi(rr); }
          if (RELU){ v0 = fmaxf(v0, 0.f); v1 = fmaxf(v1, 0.f); }
          outb[(size_t)row*64 + cp] = packbf(v0, v1);
        }
      }
    }
  }
}

// ---------------- graph LayerNorm on bf16-packed data ----------------
__global__ __launch_bounds__(256) void k_ln_reduce_bf(const uint* __restrict__ xb, float* __restrict__ pbuf){
  const uint4* x4 = (const uint4*)xb;
  const int n4 = NN*16;
  float s = 0.f, ss = 0.f;
  for (int i = blockIdx.x*256 + threadIdx.x; i < n4; i += gridDim.x*256){
    uint4 u = x4[i];
    float a, b;
    a = bflo(u.x); b = bfhi(u.x); s += a+b; ss += a*a + b*b;
    a = bflo(u.y); b = bfhi(u.y); s += a+b; ss += a*a + b*b;
    a = bflo(u.z); b = bfhi(u.z); s += a+b; ss += a*a + b*b;
    a = bflo(u.w); b = bfhi(u.w); s += a+b; ss += a*a + b*b;
  }
  #pragma unroll
  for (int m = 32; m >= 1; m >>= 1){ s += __shfl_xor(s, m, 64); ss += __shfl_xor(ss, m, 64); }
  __shared__ float sh[8];
  int wid = threadIdx.x >> 6, lane = threadIdx.x & 63;
  if (lane == 0){ sh[wid*2] = s; sh[wid*2+1] = ss; }
  __syncthreads();
  if (threadIdx.x == 0){
    float S = 0.f, SS = 0.f;
    for (int w = 0; w < 4; ++w){ S += sh[2*w]; SS += sh[2*w+1]; }
    pbuf[blockIdx.x*2] = S; pbuf[blockIdx.x*2+1] = SS;
  }
}

__global__ __launch_bounds__(256) void k_ln_stats(const float* __restrict__ pbuf, float* __restrict__ stats, int nb){
  float s = 0.f, ss = 0.f;
  for (int i = threadIdx.x; i < nb; i += 256){ s += pbuf[2*i]; ss += pbuf[2*i+1]; }
  #pragma unroll
  for (int m = 32; m >= 1; m >>= 1){ s += __shfl_xor(s, m, 64); ss += __shfl_xor(ss, m, 64); }
  __shared__ float sh[8];
  int wid = threadIdx.x >> 6, lane = threadIdx.x & 63;
  if (lane == 0){ sh[wid*2] = s; sh[wid*2+1] = ss; }
  __syncthreads();
  if (threadIdx.x == 0){
    float S = 0.f, SS = 0.f;
    for (int w = 0; w < 4; ++w){ S += sh[2*w]; SS += sh[2*w+1]; }
    const float inv = 1.f/((float)NN*(float)DD);
    float mu = S*inv;
    float var = SS*inv - mu*mu;
    stats[0] = mu;
    stats[1] = rsqrtf(var + 1e-5f);
  }
}

__global__ __launch_bounds__(256) void k_ln_apply_bf(uint* __restrict__ xb, const float* __restrict__ g,
    const float* __restrict__ be, const float* __restrict__ stats){
  const int n4 = NN*16;
  float mu = stats[0], rs = stats[1];
  uint4* x4 = (uint4*)xb;
  const float2* g2 = (const float2*)g;
  const float2* b2 = (const float2*)be;
  for (int i = blockIdx.x*256 + threadIdx.x; i < n4; i += gridDim.x*256){
    int cb = (i & 15)*4;
    uint4 u = x4[i];
    float2 ga = g2[cb],   gb = g2[cb+1], gc = g2[cb+2], gd = g2[cb+3];
    float2 ba = b2[cb],   bb = b2[cb+1], bc = b2[cb+2], bd = b2[cb+3];
    u.x = packbf((bflo(u.x)-mu)*rs*ga.x + ba.x, (bfhi(u.x)-mu)*rs*ga.y + ba.y);
    u.y = packbf((bflo(u.y)-mu)*rs*gb.x + bb.x, (bfhi(u.y)-mu)*rs*gb.y + bb.y);
    u.z = packbf((bflo(u.z)-mu)*rs*gc.x + bc.x, (bfhi(u.z)-mu)*rs*gc.y + bc.y);
    u.w = packbf((bflo(u.w)-mu)*rs*gd.x + bd.x, (bfhi(u.w)-mu)*rs*gd.y + bd.y);
    x4[i] = u;
  }
}

// ---------------- fused LN2-apply + final dot: val[n] = LN(h[n]).fcw + fcb ----------------
__global__ __launch_bounds__(256) void k_fdot_ln(const uint* __restrict__ xb, const float* __restrict__ g,
    const float* __restrict__ be, const float* __restrict__ stats,
    const float* __restrict__ fw, const float* __restrict__ fb, float* __restrict__ val){
  int n = blockIdx.x*4 + (threadIdx.x >> 6);
  if (n >= NN) return;
  int lane = threadIdx.x & 63;
  float mu = stats[0], rs = stats[1];
  uint p = xb[(size_t)n*64 + lane];
  float2 gg = ((const float2*)g)[lane];
  float2 bb = ((const float2*)be)[lane];
  float2 ww = ((const float2*)fw)[lane];
  float v = ((bflo(p)-mu)*rs*gg.x + bb.x)*ww.x + ((bfhi(p)-mu)*rs*gg.y + bb.y)*ww.y;
  #pragma unroll
  for (int m = 32; m >= 1; m >>= 1) v += __shfl_xor(v, m, 64);
  if (lane == 0) val[n] = v + fb[0];
}

// ---------------- segment mean over sorted batch ----------------
__global__ __launch_bounds__(64) void k_pool(const float* __restrict__ val, const int* __restrict__ batch,
                                             float* __restrict__ out){
  int g = blockIdx.x;
  int lane = threadIdx.x;
  int lo = 0, hi = NN;
  while (lo < hi){ int mid = (lo+hi)>>1; if (batch[mid] < g) lo = mid+1; else hi = mid; }
  int start = lo;
  hi = NN;
  while (lo < hi){ int mid = (lo+hi)>>1; if (batch[mid] < g+1) lo = mid+1; else hi = mid; }
  int end = lo;
  float s = 0.f;
  for (int i = start + lane; i < end; i += 64) s += val[i];
  #pragma unroll
  for (int m = 32; m >= 1; m >>= 1) s += __shfl_xor(s, m, 64);
  if (lane == 0) out[g] = s / fmaxf((float)(end - start), 1.f);
}

extern "C" void kernel_launch(void* const* d_in, const int* in_sizes, int n_in,
                              void* d_out, int out_size, void* d_ws, size_t ws_size,
                              hipStream_t stream){
  const float* x   = (const float*)d_in[0];
  const int*   ei  = (const int*)d_in[1];
  const int* batch = (const int*)d_in[2];
  const float* W1  = (const float*)d_in[3];
  const float* as1 = (const float*)d_in[4];
  const float* ad1 = (const float*)d_in[5];
  const float* b1  = (const float*)d_in[6];
  const float* W2  = (const float*)d_in[7];
  const float* as2 = (const float*)d_in[8];
  const float* ad2 = (const float*)d_in[9];
  const float* b2  = (const float*)d_in[10];
  const float* fc1w= (const float*)d_in[11];
  const float* fc1b= (const float*)d_in[12];
  const float* fc2w= (const float*)d_in[13];
  const float* fc2b= (const float*)d_in[14];
  const float* fc3w= (const float*)d_in[15];
  const float* fc3b= (const float*)d_in[16];
  const float* fc4w= (const float*)d_in[17];
  const float* fc4b= (const float*)d_in[18];
  const float* g1  = (const float*)d_in[19];
  const float* be1 = (const float*)d_in[20];
  const float* g2  = (const float*)d_in[21];
  const float* be2 = (const float*)d_in[22];
  const float* fcw = (const float*)d_in[23];
  const float* fcb = (const float*)d_in[24];
  float* out = (float*)d_out;
  (void)in_sizes; (void)n_in; (void)out_size; (void)ws_size;

  char* ws = (char*)d_ws;
  size_t off = 0;
  auto alloc = [&](size_t bytes)->void*{
    void* p = ws + off;
    off += (bytes + 255) & ~(size_t)255;
    return p;
  };
  float* A    = (float*)alloc((size_t)NN*DD*4);   // aliases: hist (CSR), t1b/t2b, fc1/fc3 out (bf16)
  float* B    = (float*)alloc((size_t)NN*DD*4);   // h1 / gat2-out / fc4-out (bf16)
  float* C    = (float*)alloc((size_t)NN*DD*4);   // alpha1 [E,8] f32, then fc2-out/LN1 (bf16)
  float* als1 = (float*)alloc((size_t)NN*NH*4);
  float* ald1 = (float*)alloc((size_t)NN*NH*4);
  float* a0n1 = (float*)alloc((size_t)NN*NH*4);
  float* inv1 = (float*)alloc((size_t)NN*NH*4);
  float* als2 = (float*)alloc((size_t)NN*4);
  float* ald2 = (float*)alloc((size_t)NN*4);
  float* a0n2 = (float*)alloc((size_t)NN*4);
  float* inv2 = (float*)alloc((size_t)NN*4);
  float* alpha2 = (float*)alloc((size_t)NE*4);    // alias: ebuf during CSR build
  int*   rowptr = (int*)alloc((size_t)(NN+1)*4);
  int*   col    = (int*)alloc((size_t)NE*4);
  int*   bsum   = (int*)alloc((size_t)NBK*4);
  int*   bbase  = (int*)alloc((size_t)NBK*4);
  float* pbuf   = (float*)alloc(1024*2*4);
  float* stats  = (float*)alloc(2*4);
  float* val    = (float*)alloc((size_t)NN*4);
  uint* wt_fc1  = (uint*)alloc((size_t)DD*64*4);
  uint* wt_fc2  = (uint*)alloc((size_t)DD*64*4);
  uint* wt_w2   = (uint*)alloc((size_t)DD*64*4);
  uint* wt_fc3  = (uint*)alloc((size_t)DD*64*4);
  uint* wt_fc4  = (uint*)alloc((size_t)DD*64*4);

  float* alpha1 = C;            // C dead until fc2 output
  uint*  Ab     = (uint*)A;
  uint*  Bb     = (uint*)B;
  uint*  Cb     = (uint*)C;
  int*   hist   = (int*)A;      // A dead during CSR build
  uint*  ebuf   = (uint*)alpha2;

  const int* esrc = ei;
  const int* edst = ei + NE;

  // ---- CSR build (atomic-free partition) ----
  k_hist <<<NBLK, 512, 0, stream>>>(edst, hist);
  k_bsum <<<(NBK+255)/256, 256, 0, stream>>>(hist, bsum);
  k_bscan<<<1, 1024, 0, stream>>>(bsum, bbase);
  k_part <<<NBLK, 512, 0, stream>>>(esrc, edst, hist, bbase, ebuf);
  k_fin  <<<NBK, 64, 0, stream>>>(ebuf, bbase, bsum, rowptr, col);

  // ---- weight transpose+convert to bf16 (tiny) ----
  k_wconv<<<DD, 64, 0, stream>>>(fc1w, wt_fc1);
  k_wconv<<<DD, 64, 0, stream>>>(fc2w, wt_fc2);
  k_wconv<<<DD, 64, 0, stream>>>(W2,   wt_w2);
  k_wconv<<<DD, 64, 0, stream>>>(fc3w, wt_fc3);
  k_wconv<<<DD, 64, 0, stream>>>(fc4w, wt_fc4);

  const int WB = (NN + 3)/4;     // wave-per-node kernels
  const int GB = (NN + 127)/128; // MFMA GEMM blocks

  // GAT layer 1 (bf16 feature table in Ab)
  k_lin1<<<NN, 128, 0, stream>>>(x, W1, as1, ad1, Ab, als1, ald1);
  k_attn1<<<WB, 256, 0, stream>>>(als1, ald1, rowptr, col, alpha1, a0n1, inv1);
  k_gat1g<<<WB, 256, 0, stream>>>(Ab, alpha1, a0n1, inv1, rowptr, col, b1, Bb);

  // fc1 (relu) -> Ab ; fc2 (+res h1, relu) -> Cb
  k_mfma<true,  true, false><<<GB, 256, 0, stream>>>(Bb, wt_fc1, fc1b, nullptr, Ab, NN);
  k_mfma<true,  true, true ><<<GB, 256, 0, stream>>>(Ab, wt_fc2, fc2b, Bb,      Cb, NN);

  // LN1 (graph mode, bf16 in place)
  k_ln_reduce_bf<<<1024, 256, 0, stream>>>(Cb, pbuf);
  k_ln_stats<<<1, 256, 0, stream>>>(pbuf, stats, 1024);
  k_ln_apply_bf<<<1024, 256, 0, stream>>>(Cb, g1, be1, stats);

  // GAT layer 2: t2b = Cb @ W2 -> Ab
  k_mfma<false, false, false><<<GB, 256, 0, stream>>>(Cb, wt_w2, nullptr, nullptr, Ab, NN);
  k_al2<<<WB, 256, 0, stream>>>(Ab, as2, ad2, als2, ald2);
  k_attn2<<<WB, 256, 0, stream>>>(als2, ald2, rowptr, col, alpha2, a0n2, inv2);
  k_gat2g<<<WB, 256, 0, stream>>>(Ab, alpha2, a0n2, inv2, rowptr, col, b2, Bb);

  // fc3 (relu) -> Ab ; fc4 (+res LN1-out Cb) -> Bb
  k_mfma<true,  true, false><<<GB, 256, 0, stream>>>(Bb, wt_fc3, fc3b, nullptr, Ab, NN);
  k_mfma<false, true, true ><<<GB, 256, 0, stream>>>(Ab, wt_fc4, fc4b, Cb,      Bb, NN);

  // LN2 stats, then fused LN2-apply + final dot
  k_ln_reduce_bf<<<1024, 256, 0, stream>>>(Bb, pbuf);
  k_ln_stats<<<1, 256, 0, stream>>>(pbuf, stats, 1024);
  k_fdot_ln<<<WB, 256, 0, stream>>>(Bb, g2, be2, stats, fcw, fcb, val);
  k_pool<<<NG, 64, 0, stream>>>(val, batch, out);
}

// Round 7
// 483.981 us; speedup vs baseline: 2.7645x; 1.1599x over previous
//
#include <hip/hip_runtime.h>
#include <cstdint>

#define NN 100000
#define NE 1600000
#define DI 9
#define DD 128
#define NH 8
#define NG 1000

#define NBK 3125            // buckets = dst>>5; 3125*32 == 100000 exactly
#define NBLK 256            // partition blocks
#define EPB (NE/NBLK)       // 6250 edges per block (exact)

typedef unsigned int uint;
typedef __attribute__((ext_vector_type(8))) short bf16x8;
typedef __attribute__((ext_vector_type(4))) float f32x4;

__device__ __forceinline__ float leaky(float x){ return x > 0.f ? x : 0.2f*x; }
__device__ __forceinline__ uint f2bf(float f){            // round-to-nearest-even bf16
  uint u = __float_as_uint(f);
  return (u + 0x7fffu + ((u>>16)&1u)) >> 16;
}
__device__ __forceinline__ float bflo(uint p){ return __uint_as_float(p << 16); }
__device__ __forceinline__ float bfhi(uint p){ return __uint_as_float(p & 0xffff0000u); }
__device__ __forceinline__ uint packbf(float a, float b){ return f2bf(a) | (f2bf(b)<<16); }

union U16 { uint4 u; bf16x8 v; };
__device__ __forceinline__ bf16x8 ld8(const uint* p){ U16 t; t.u = *(const uint4*)p; return t.v; }

// ================= CSR build: atomic-free bucket partition =================
__global__ __launch_bounds__(512) void k_hist(const int* __restrict__ dst, int* __restrict__ hist){
  __shared__ int h[NBK];
  for (int i = threadIdx.x; i < NBK; i += 512) h[i] = 0;
  __syncthreads();
  int blk = blockIdx.x;
  int beg = blk*EPB, end = beg + EPB;
  for (int i = beg + threadIdx.x; i < end; i += 512)
    atomicAdd(&h[dst[i] >> 5], 1);
  __syncthreads();
  for (int b = threadIdx.x; b < NBK; b += 512) hist[(size_t)blk*NBK + b] = h[b];
}

__global__ __launch_bounds__(256) void k_bsum(int* __restrict__ hist, int* __restrict__ bsum){
  int b = blockIdx.x*256 + threadIdx.x;
  if (b >= NBK) return;
  int run = 0;
  for (int k = 0; k < NBLK; ++k){
    int t = hist[(size_t)k*NBK + b];
    hist[(size_t)k*NBK + b] = run;
    run += t;
  }
  bsum[b] = run;
}

__global__ __launch_bounds__(1024) void k_bscan(const int* __restrict__ bsum, int* __restrict__ bbase){
  __shared__ int sh[1024];
  __shared__ int carry;
  if (threadIdx.x == 0) carry = 0;
  __syncthreads();
  for (int c0 = 0; c0 < NBK; c0 += 1024){
    int i = c0 + threadIdx.x;
    int v = (i < NBK) ? bsum[i] : 0;
    sh[threadIdx.x] = v;
    __syncthreads();
    for (int off = 1; off < 1024; off <<= 1){
      int t = (threadIdx.x >= off) ? sh[threadIdx.x-off] : 0;
      __syncthreads();
      sh[threadIdx.x] += t;
      __syncthreads();
    }
    if (i < NBK) bbase[i] = carry + sh[threadIdx.x] - v;
    __syncthreads();
    if (threadIdx.x == 0) carry += sh[1023];
    __syncthreads();
  }
}

__global__ __launch_bounds__(512) void k_part(const int* __restrict__ src, const int* __restrict__ dst,
    const int* __restrict__ hist, const int* __restrict__ bbase, uint* __restrict__ ebuf){
  __shared__ int cur[NBK];
  int blk = blockIdx.x;
  for (int b = threadIdx.x; b < NBK; b += 512)
    cur[b] = hist[(size_t)blk*NBK + b] + bbase[b];
  __syncthreads();
  int beg = blk*EPB, end = beg + EPB;
  for (int i = beg + threadIdx.x; i < end; i += 512){
    int d = dst[i], s = src[i];
    int b = d >> 5;
    int p = atomicAdd(&cur[b], 1);              // LDS atomic
    ebuf[p] = (uint)s | ((uint)(d & 31) << 26);
  }
}

__global__ __launch_bounds__(64) void k_fin(const uint* __restrict__ ebuf, const int* __restrict__ bbase,
    const int* __restrict__ bsum, int* __restrict__ rowptr, int* __restrict__ col){
  __shared__ int cnt32[32];
  __shared__ int exc[32];
  int b = blockIdx.x;
  int lane = threadIdx.x;
  if (lane < 32) cnt32[lane] = 0;
  __syncthreads();
  int base = bbase[b], n = bsum[b];
  for (int i = lane; i < n; i += 64)
    atomicAdd(&cnt32[ebuf[base+i] >> 26], 1);
  __syncthreads();
  if (lane == 0){
    int run = 0;
    for (int d = 0; d < 32; ++d){
      int t = cnt32[d];
      exc[d] = run;
      rowptr[b*32 + d] = base + run;
      run += t;
    }
  }
  __syncthreads();
  if (lane < 32) cnt32[lane] = exc[lane];
  __syncthreads();
  for (int i = lane; i < n; i += 64){
    uint e = ebuf[base+i];
    int d = e >> 26;
    int r = atomicAdd(&cnt32[d], 1);
    col[base + r] = (int)(e & 0x03ffffffu);
  }
  if (b == 0 && lane == 0) rowptr[NN] = NE;
}

// ---------------- weight convert: WT_bf16[n][k] packed, from W[k][n] f32 ----------------
__global__ __launch_bounds__(64) void k_wconv(const float* __restrict__ W, uint* __restrict__ WT){
  int n = blockIdx.x;
  int t = threadIdx.x;
  float w0 = W[(2*t)*DD + n];
  float w1 = W[(2*t+1)*DD + n];
  WT[n*64 + t] = packbf(w0, w1);
}

// ---------------- GAT1 linear (x@W1) + logits; writes bf16-packed feature table ----------------
__global__ __launch_bounds__(128) void k_lin1(const float* __restrict__ x, const float* __restrict__ W1,
    const float* __restrict__ as1, const float* __restrict__ ad1,
    uint* __restrict__ t1b, float* __restrict__ al_s, float* __restrict__ al_d){
  int n = blockIdx.x;
  int c = threadIdx.x;
  const float* xr = x + n*DI;
  float t = 0.f;
  #pragma unroll
  for (int k = 0; k < DI; ++k) t = fmaf(xr[k], W1[k*DD+c], t);
  uint mybf = f2bf(t);
  uint pbf  = (uint)__shfl_xor((int)mybf, 1, 64);
  if (!(c & 1)) t1b[(size_t)n*64 + (c>>1)] = mybf | (pbf<<16);
  float vs = t * as1[c];
  float vd = t * ad1[c];
  #pragma unroll
  for (int m = 8; m >= 1; m >>= 1){ vs += __shfl_xor(vs, m, 16); vd += __shfl_xor(vd, m, 16); }
  if ((c & 15) == 0){
    al_s[n*NH + (c>>4)] = vs;
    al_d[n*NH + (c>>4)] = vd;
  }
}

// ---------------- GAT1 fused: inline softmax (no max-shift) + gather + b1 + ReLU ----------------
__global__ __launch_bounds__(256) void k_gat1(const uint* __restrict__ t1b,
    const float* __restrict__ al_s, const float* __restrict__ al_d,
    const int* __restrict__ rowptr, const int* __restrict__ col,
    const float* __restrict__ b1, uint* __restrict__ outb){
  int n = blockIdx.x*4 + (threadIdx.x >> 6);
  if (n >= NN) return;
  uint lane = threadIdx.x & 63;
  uint h = lane >> 3;                    // head of channels (2*lane, 2*lane+1)
  float ald = al_d[(uint)n*NH + h];
  float a0  = __expf(leaky(al_s[(uint)n*NH + h] + ald));   // self-loop
  uint  ps  = t1b[(uint)n*64u + lane];
  float den = a0;
  float s0 = a0*bflo(ps), s1 = a0*bfhi(ps);
  int beg = rowptr[n], end = rowptr[n+1];
  int e = beg;
  for (; e + 4 <= end; e += 4){
    uint c0 = (uint)col[e], c1 = (uint)col[e+1], c2 = (uint)col[e+2], c3 = (uint)col[e+3];
    float l0 = al_s[c0*8u + h], l1 = al_s[c1*8u + h];
    float l2 = al_s[c2*8u + h], l3 = al_s[c3*8u + h];
    uint p0 = t1b[c0*64u + lane];
    uint p1 = t1b[c1*64u + lane];
    uint p2 = t1b[c2*64u + lane];
    uint p3 = t1b[c3*64u + lane];
    float a0_ = __expf(leaky(l0 + ald));
    float a1_ = __expf(leaky(l1 + ald));
    float a2_ = __expf(leaky(l2 + ald));
    float a3_ = __expf(leaky(l3 + ald));
    den += a0_ + a1_ + a2_ + a3_;
    s0 = fmaf(a0_, bflo(p0), s0); s1 = fmaf(a0_, bfhi(p0), s1);
    s0 = fmaf(a1_, bflo(p1), s0); s1 = fmaf(a1_, bfhi(p1), s1);
    s0 = fmaf(a2_, bflo(p2), s0); s1 = fmaf(a2_, bfhi(p2), s1);
    s0 = fmaf(a3_, bflo(p3), s0); s1 = fmaf(a3_, bfhi(p3), s1);
  }
  for (; e < end; ++e){
    uint c = (uint)col[e];
    float a = __expf(leaky(al_s[c*8u + h] + ald));
    uint p = t1b[c*64u + lane];
    den += a;
    s0 = fmaf(a, bflo(p), s0); s1 = fmaf(a, bfhi(p), s1);
  }
  float inv = 1.f/(den + 1e-16f);
  float2 bb = ((const float2*)b1)[lane];
  outb[(uint)n*64u + lane] = packbf(fmaxf(s0*inv + bb.x, 0.f), fmaxf(s1*inv + bb.y, 0.f));
}

// ---------------- GAT2 attention logits from bf16 table ----------------
__global__ __launch_bounds__(256) void k_al2(const uint* __restrict__ t2b,
    const float* __restrict__ as2, const float* __restrict__ ad2,
    float* __restrict__ al_s, float* __restrict__ al_d){
  int n = blockIdx.x*4 + (threadIdx.x >> 6);
  if (n >= NN) return;
  int lane = threadIdx.x & 63;
  uint p = t2b[(size_t)n*64 + lane];
  float v0 = bflo(p), v1 = bfhi(p);
  float2 s2 = ((const float2*)as2)[lane];
  float2 d2 = ((const float2*)ad2)[lane];
  float vs = v0*s2.x + v1*s2.y;
  float vd = v0*d2.x + v1*d2.y;
  #pragma unroll
  for (int m = 32; m >= 1; m >>= 1){ vs += __shfl_xor(vs, m, 64); vd += __shfl_xor(vd, m, 64); }
  if (lane == 0){ al_s[n] = vs; al_d[n] = vd; }
}

// ---------------- GAT2 fused: inline softmax + gather + b2 (no relu) ----------------
__global__ __launch_bounds__(256) void k_gat2(const uint* __restrict__ t2b,
    const float* __restrict__ al_s, const float* __restrict__ al_d,
    const int* __restrict__ rowptr, const int* __restrict__ col,
    const float* __restrict__ b2, uint* __restrict__ outb){
  int n = blockIdx.x*4 + (threadIdx.x >> 6);
  if (n >= NN) return;
  uint lane = threadIdx.x & 63;
  float ald = al_d[n];
  float a0  = __expf(leaky(al_s[n] + ald));
  uint  ps  = t2b[(uint)n*64u + lane];
  float den = a0;
  float s0 = a0*bflo(ps), s1 = a0*bfhi(ps);
  int beg = rowptr[n], end = rowptr[n+1];
  int e = beg;
  for (; e + 4 <= end; e += 4){
    uint c0 = (uint)col[e], c1 = (uint)col[e+1], c2 = (uint)col[e+2], c3 = (uint)col[e+3];
    float l0 = al_s[c0], l1 = al_s[c1], l2 = al_s[c2], l3 = al_s[c3];
    uint p0 = t2b[c0*64u + lane];
    uint p1 = t2b[c1*64u + lane];
    uint p2 = t2b[c2*64u + lane];
    uint p3 = t2b[c3*64u + lane];
    float a0_ = __expf(leaky(l0 + ald));
    float a1_ = __expf(leaky(l1 + ald));
    float a2_ = __expf(leaky(l2 + ald));
    float a3_ = __expf(leaky(l3 + ald));
    den += a0_ + a1_ + a2_ + a3_;
    s0 = fmaf(a0_, bflo(p0), s0); s1 = fmaf(a0_, bfhi(p0), s1);
    s0 = fmaf(a1_, bflo(p1), s0); s1 = fmaf(a1_, bfhi(p1), s1);
    s0 = fmaf(a2_, bflo(p2), s0); s1 = fmaf(a2_, bfhi(p2), s1);
    s0 = fmaf(a3_, bflo(p3), s0); s1 = fmaf(a3_, bfhi(p3), s1);
  }
  for (; e < end; ++e){
    uint c = (uint)col[e];
    float a = __expf(leaky(al_s[c] + ald));
    uint p = t2b[c*64u + lane];
    den += a;
    s0 = fmaf(a, bflo(p), s0); s1 = fmaf(a, bfhi(p), s1);
  }
  float inv = 1.f/(den + 1e-16f);
  float2 bb = ((const float2*)b2)[lane];
  outb[(uint)n*64u + lane] = packbf(s0*inv + bb.x, s1*inv + bb.y);
}

// ---------------- MFMA bf16 GEMM: [M,128]x[128,128], LDS-free, fused epilogue ----------------
// A frag: lane holds X[m0 + (lane&15)][k = 32*kk + (lane>>4)*8 + j]   (8 contiguous bf16)
// B frag: lane holds W[k][n0c + (lane&15)] = WT[n0c+(lane&15)][k...]  (8 contiguous bf16)
// C/D:    lane reg r holds OUT[m0 + (lane>>4)*4 + r][n0c + (lane&15)] (m89-verified)
// LNRED: also emit per-block (sum, sumsq) of final outputs -> pbuf[blockIdx*2]
template<bool RELU, bool BIAS, bool RES, bool LNRED>
__global__ __launch_bounds__(256) void k_mfma(const uint* __restrict__ Xb, const uint* __restrict__ WTb,
    const float* __restrict__ bias, const uint* __restrict__ resb, uint* __restrict__ outb,
    float* __restrict__ pbuf, int nrows){
  int lane = threadIdx.x & 63;
  int wid  = threadIdx.x >> 6;
  int m0 = blockIdx.x*128 + wid*32;
  int lr = lane & 15, hi4 = lane >> 4;
  f32x4 acc[2][8];
  #pragma unroll
  for (int a = 0; a < 2; ++a)
    #pragma unroll
    for (int c = 0; c < 8; ++c) acc[a][c] = (f32x4){0.f,0.f,0.f,0.f};
  int ra0 = m0 + lr;      if (ra0 > NN-1) ra0 = NN-1;
  int ra1 = m0 + 16 + lr; if (ra1 > NN-1) ra1 = NN-1;
  #pragma unroll
  for (int kk = 0; kk < 4; ++kk){
    int ko = kk*16 + hi4*4;                 // uint offset within row (32 bf16 per kk)
    bf16x8 a0 = ld8(Xb + (size_t)ra0*64 + ko);
    bf16x8 a1 = ld8(Xb + (size_t)ra1*64 + ko);
    #pragma unroll
    for (int c = 0; c < 8; ++c){
      bf16x8 b = ld8(WTb + (size_t)(c*16 + lr)*64 + ko);
      acc[0][c] = __builtin_amdgcn_mfma_f32_16x16x32_bf16(a0, b, acc[0][c], 0, 0, 0);
      acc[1][c] = __builtin_amdgcn_mfma_f32_16x16x32_bf16(a1, b, acc[1][c], 0, 0, 0);
    }
  }
  bool evn = !(lane & 1);
  int cph = lr >> 1;
  float lns = 0.f, lnss = 0.f;
  #pragma unroll
  for (int rg = 0; rg < 2; ++rg){
    #pragma unroll
    for (int c = 0; c < 8; ++c){
      int cp = c*8 + cph;
      #pragma unroll
      for (int r = 0; r < 4; ++r){
        float v0 = acc[rg][c][r];
        float v1 = __shfl_xor(v0, 1, 64);   // partner lane holds col+1 (even lanes use it)
        int row = m0 + rg*16 + hi4*4 + r;
        if (evn && row < nrows){
          if (BIAS){ float2 bb = ((const float2*)bias)[cp]; v0 += bb.x; v1 += bb.y; }
          if (RES){ uint rr = resb[(size_t)row*64 + cp]; v0 += bflo(rr); v1 += bfhi(rr); }
          if (RELU){ v0 = fmaxf(v0, 0.f); v1 = fmaxf(v1, 0.f); }
          outb[(size_t)row*64 + cp] = packbf(v0, v1);
          if (LNRED){ lns += v0 + v1; lnss += v0*v0 + v1*v1; }
        }
      }
    }
  }
  if (LNRED){
    #pragma unroll
    for (int m = 32; m >= 1; m >>= 1){ lns += __shfl_xor(lns, m, 64); lnss += __shfl_xor(lnss, m, 64); }
    __shared__ float shred[8];
    if (lane == 0){ shred[wid*2] = lns; shred[wid*2+1] = lnss; }
    __syncthreads();
    if (threadIdx.x == 0){
      float S = 0.f, SS = 0.f;
      for (int w = 0; w < 4; ++w){ S += shred[2*w]; SS += shred[2*w+1]; }
      pbuf[blockIdx.x*2] = S; pbuf[blockIdx.x*2+1] = SS;
    }
  }
}

// ---------------- LN stats from per-block partials ----------------
__global__ __launch_bounds__(256) void k_ln_stats(const float* __restrict__ pbuf, float* __restrict__ stats, int nb){
  float s = 0.f, ss = 0.f;
  for (int i = threadIdx.x; i < nb; i += 256){ s += pbuf[2*i]; ss += pbuf[2*i+1]; }
  #pragma unroll
  for (int m = 32; m >= 1; m >>= 1){ s += __shfl_xor(s, m, 64); ss += __shfl_xor(ss, m, 64); }
  __shared__ float sh[8];
  int wid = threadIdx.x >> 6, lane = threadIdx.x & 63;
  if (lane == 0){ sh[wid*2] = s; sh[wid*2+1] = ss; }
  __syncthreads();
  if (threadIdx.x == 0){
    float S = 0.f, SS = 0.f;
    for (int w = 0; w < 4; ++w){ S += sh[2*w]; SS += sh[2*w+1]; }
    const float inv = 1.f/((float)NN*(float)DD);
    float mu = S*inv;
    float var = SS*inv - mu*mu;
    stats[0] = mu;
    stats[1] = rsqrtf(var + 1e-5f);
  }
}

__global__ __launch_bounds__(256) void k_ln_apply_bf(uint* __restrict__ xb, const float* __restrict__ g,
    const float* __restrict__ be, const float* __restrict__ stats){
  const int n4 = NN*16;
  float mu = stats[0], rs = stats[1];
  uint4* x4 = (uint4*)xb;
  const float2* g2 = (const float2*)g;
  const float2* b2 = (const float2*)be;
  for (int i = blockIdx.x*256 + threadIdx.x; i < n4; i += gridDim.x*256){
    int cb = (i & 15)*4;
    uint4 u = x4[i];
    float2 ga = g2[cb],   gb = g2[cb+1], gc = g2[cb+2], gd = g2[cb+3];
    float2 ba = b2[cb],   bb = b2[cb+1], bc = b2[cb+2], bd = b2[cb+3];
    u.x = packbf((bflo(u.x)-mu)*rs*ga.x + ba.x, (bfhi(u.x)-mu)*rs*ga.y + ba.y);
    u.y = packbf((bflo(u.y)-mu)*rs*gb.x + bb.x, (bfhi(u.y)-mu)*rs*gb.y + bb.y);
    u.z = packbf((bflo(u.z)-mu)*rs*gc.x + bc.x, (bfhi(u.z)-mu)*rs*gc.y + bc.y);
    u.w = packbf((bflo(u.w)-mu)*rs*gd.x + bd.x, (bfhi(u.w)-mu)*rs*gd.y + bd.y);
    x4[i] = u;
  }
}

// ---------------- fused LN2-apply + final dot: val[n] = LN(h[n]).fcw + fcb ----------------
__global__ __launch_bounds__(256) void k_fdot_ln(const uint* __restrict__ xb, const float* __restrict__ g,
    const float* __restrict__ be, const float* __restrict__ stats,
    const float* __restrict__ fw, const float* __restrict__ fb, float* __restrict__ val){
  int n = blockIdx.x*4 + (threadIdx.x >> 6);
  if (n >= NN) return;
  int lane = threadIdx.x & 63;
  float mu = stats[0], rs = stats[1];
  uint p = xb[(size_t)n*64 + lane];
  float2 gg = ((const float2*)g)[lane];
  float2 bb = ((const float2*)be)[lane];
  float2 ww = ((const float2*)fw)[lane];
  float v = ((bflo(p)-mu)*rs*gg.x + bb.x)*ww.x + ((bfhi(p)-mu)*rs*gg.y + bb.y)*ww.y;
  #pragma unroll
  for (int m = 32; m >= 1; m >>= 1) v += __shfl_xor(v, m, 64);
  if (lane == 0) val[n] = v + fb[0];
}

// ---------------- segment mean over sorted batch ----------------
__global__ __launch_bounds__(64) void k_pool(const float* __restrict__ val, const int* __restrict__ batch,
                                             float* __restrict__ out){
  int g = blockIdx.x;
  int lane = threadIdx.x;
  int lo = 0, hi = NN;
  while (lo < hi){ int mid = (lo+hi)>>1; if (batch[mid] < g) lo = mid+1; else hi = mid; }
  int start = lo;
  hi = NN;
  while (lo < hi){ int mid = (lo+hi)>>1; if (batch[mid] < g+1) lo = mid+1; else hi = mid; }
  int end = lo;
  float s = 0.f;
  for (int i = start + lane; i < end; i += 64) s += val[i];
  #pragma unroll
  for (int m = 32; m >= 1; m >>= 1) s += __shfl_xor(s, m, 64);
  if (lane == 0) out[g] = s / fmaxf((float)(end - start), 1.f);
}

extern "C" void kernel_launch(void* const* d_in, const int* in_sizes, int n_in,
                              void* d_out, int out_size, void* d_ws, size_t ws_size,
                              hipStream_t stream){
  const float* x   = (const float*)d_in[0];
  const int*   ei  = (const int*)d_in[1];
  const int* batch = (const int*)d_in[2];
  const float* W1  = (const float*)d_in[3];
  const float* as1 = (const float*)d_in[4];
  const float* ad1 = (const float*)d_in[5];
  const float* b1  = (const float*)d_in[6];
  const float* W2  = (const float*)d_in[7];
  const float* as2 = (const float*)d_in[8];
  const float* ad2 = (const float*)d_in[9];
  const float* b2  = (const float*)d_in[10];
  const float* fc1w= (const float*)d_in[11];
  const float* fc1b= (const float*)d_in[12];
  const float* fc2w= (const float*)d_in[13];
  const float* fc2b= (const float*)d_in[14];
  const float* fc3w= (const float*)d_in[15];
  const float* fc3b= (const float*)d_in[16];
  const float* fc4w= (const float*)d_in[17];
  const float* fc4b= (const float*)d_in[18];
  const float* g1  = (const float*)d_in[19];
  const float* be1 = (const float*)d_in[20];
  const float* g2  = (const float*)d_in[21];
  const float* be2 = (const float*)d_in[22];
  const float* fcw = (const float*)d_in[23];
  const float* fcb = (const float*)d_in[24];
  float* out = (float*)d_out;
  (void)in_sizes; (void)n_in; (void)out_size; (void)ws_size;

  char* ws = (char*)d_ws;
  size_t off = 0;
  auto alloc = [&](size_t bytes)->void*{
    void* p = ws + off;
    off += (bytes + 255) & ~(size_t)255;
    return p;
  };
  float* A    = (float*)alloc((size_t)NN*DD*4);   // aliases: hist (CSR), t1b/t2b, fc1/fc3 out (bf16)
  float* B    = (float*)alloc((size_t)NN*DD*4);   // h1 / gat2-out / fc4-out (bf16)
  float* C    = (float*)alloc((size_t)NN*DD*4);   // fc2-out / LN1-out (bf16)
  float* als1 = (float*)alloc((size_t)NN*NH*4);
  float* ald1 = (float*)alloc((size_t)NN*NH*4);
  float* als2 = (float*)alloc((size_t)NN*4);
  float* ald2 = (float*)alloc((size_t)NN*4);
  float* escr = (float*)alloc((size_t)NE*4);      // ebuf during CSR build only
  int*   rowptr = (int*)alloc((size_t)(NN+1)*4);
  int*   col    = (int*)alloc((size_t)NE*4);
  int*   bsum   = (int*)alloc((size_t)NBK*4);
  int*   bbase  = (int*)alloc((size_t)NBK*4);
  float* pbuf   = (float*)alloc(1024*2*4);
  float* stats  = (float*)alloc(2*4);
  float* val    = (float*)alloc((size_t)NN*4);
  uint* wt_fc1  = (uint*)alloc((size_t)DD*64*4);
  uint* wt_fc2  = (uint*)alloc((size_t)DD*64*4);
  uint* wt_w2   = (uint*)alloc((size_t)DD*64*4);
  uint* wt_fc3  = (uint*)alloc((size_t)DD*64*4);
  uint* wt_fc4  = (uint*)alloc((size_t)DD*64*4);

  uint*  Ab     = (uint*)A;
  uint*  Bb     = (uint*)B;
  uint*  Cb     = (uint*)C;
  int*   hist   = (int*)A;      // A dead during CSR build
  uint*  ebuf   = (uint*)escr;

  const int* esrc = ei;
  const int* edst = ei + NE;

  // ---- CSR build (atomic-free partition) ----
  k_hist <<<NBLK, 512, 0, stream>>>(edst, hist);
  k_bsum <<<(NBK+255)/256, 256, 0, stream>>>(hist, bsum);
  k_bscan<<<1, 1024, 0, stream>>>(bsum, bbase);
  k_part <<<NBLK, 512, 0, stream>>>(esrc, edst, hist, bbase, ebuf);
  k_fin  <<<NBK, 64, 0, stream>>>(ebuf, bbase, bsum, rowptr, col);

  // ---- weight transpose+convert to bf16 (tiny) ----
  k_wconv<<<DD, 64, 0, stream>>>(fc1w, wt_fc1);
  k_wconv<<<DD, 64, 0, stream>>>(fc2w, wt_fc2);
  k_wconv<<<DD, 64, 0, stream>>>(W2,   wt_w2);
  k_wconv<<<DD, 64, 0, stream>>>(fc3w, wt_fc3);
  k_wconv<<<DD, 64, 0, stream>>>(fc4w, wt_fc4);

  const int WB = (NN + 3)/4;     // wave-per-node kernels
  const int GB = (NN + 127)/128; // MFMA GEMM blocks

  // GAT layer 1 (bf16 feature table in Ab), fused softmax+gather
  k_lin1<<<NN, 128, 0, stream>>>(x, W1, as1, ad1, Ab, als1, ald1);
  k_gat1<<<WB, 256, 0, stream>>>(Ab, als1, ald1, rowptr, col, b1, Bb);

  // fc1 (relu) -> Ab ; fc2 (+res h1, relu, LN-reduce) -> Cb
  k_mfma<true,  true, false, false><<<GB, 256, 0, stream>>>(Bb, wt_fc1, fc1b, nullptr, Ab, nullptr, NN);
  k_mfma<true,  true, true,  true ><<<GB, 256, 0, stream>>>(Ab, wt_fc2, fc2b, Bb,      Cb, pbuf,    NN);

  // LN1 (graph mode, bf16 in place)
  k_ln_stats<<<1, 256, 0, stream>>>(pbuf, stats, GB);
  k_ln_apply_bf<<<1024, 256, 0, stream>>>(Cb, g1, be1, stats);

  // GAT layer 2: t2b = Cb @ W2 -> Ab, fused softmax+gather
  k_mfma<false, false, false, false><<<GB, 256, 0, stream>>>(Cb, wt_w2, nullptr, nullptr, Ab, nullptr, NN);
  k_al2<<<WB, 256, 0, stream>>>(Ab, as2, ad2, als2, ald2);
  k_gat2<<<WB, 256, 0, stream>>>(Ab, als2, ald2, rowptr, col, b2, Bb);

  // fc3 (relu) -> Ab ; fc4 (+res LN1-out Cb, LN-reduce) -> Bb
  k_mfma<true,  true, false, false><<<GB, 256, 0, stream>>>(Bb, wt_fc3, fc3b, nullptr, Ab, nullptr, NN);
  k_mfma<false, true, true,  true ><<<GB, 256, 0, stream>>>(Ab, wt_fc4, fc4b, Cb,      Bb, pbuf,    NN);

  // LN2 stats, fused LN2-apply + final dot, pool
  k_ln_stats<<<1, 256, 0, stream>>>(pbuf, stats, GB);
  k_fdot_ln<<<WB, 256, 0, stream>>>(Bb, g2, be2, stats, fcw, fcb, val);
  k_pool<<<NG, 64, 0, stream>>>(val, batch, out);
}